// Round 13
// baseline (581.089 us; speedup 1.0000x reference)
//
#include <hip/hip_runtime.h>
#include <hip/hip_bf16.h>
#include <math.h>

// Problem constants (AttentionWriter): B=8,S=1024,M=2048,D=512,H=512,NH=8,Dh=64
#define BB 8
#define SS 1024
#define MM 2048
#define DD 512
#define HH 512
#define NHEAD 8
#define DHEAD 64

typedef __attribute__((ext_vector_type(8))) short short8;
typedef __attribute__((ext_vector_type(4))) float f32x4;
typedef unsigned short us;

// bf16 split helpers — native cvt (v_cvt_pk_bf16_f32), RNE
__device__ __forceinline__ us bf_hi(float x) {
    __hip_bfloat16 h = __float2bfloat16(x);
    return *reinterpret_cast<const us*>(&h);
}
__device__ __forceinline__ float bf_f(us h) {
    return __uint_as_float(((unsigned)h) << 16);
}
__device__ __forceinline__ void split_pack4(float a, float b, float c, float d,
                                            uint2& hp, uint2& lp) {
    us h0 = bf_hi(a), h1 = bf_hi(b), h2 = bf_hi(c), h3 = bf_hi(d);
    hp.x = (unsigned)h0 | ((unsigned)h1 << 16);
    hp.y = (unsigned)h2 | ((unsigned)h3 << 16);
    us l0 = bf_hi(a - bf_f(h0)), l1 = bf_hi(b - bf_f(h1));
    us l2 = bf_hi(c - bf_f(h2)), l3 = bf_hi(d - bf_f(h3));
    lp.x = (unsigned)l0 | ((unsigned)l1 << 16);
    lp.y = (unsigned)l2 | ((unsigned)l3 << 16);
}

// async global->LDS DMA, 16B per lane; LDS dest = wave-uniform base + lane*16
__device__ __forceinline__ void gload_lds16(const void* g, void* l) {
    __builtin_amdgcn_global_load_lds(
        (__attribute__((address_space(1))) void*)(g),
        (__attribute__((address_space(3))) void*)(l), 16, 0, 0);
}

struct TSB {
    const float* src[6];
    us* dh[6];
    us* dl[6];
    int nc[6];
};

// ---------------------------------------------------------------------------
// MERGED prep: [0,2048) copy+split memory_bank; [2048,2056) zero rowmeanv;
// [2056,2060) bkv concat; [2060,2062) bq_eff = b_in@Wq + bq;
// [2062,2062+1536) 6x weight transpose+split
// ---------------------------------------------------------------------------
__global__ __launch_bounds__(256) void prep_all(
    const float* __restrict__ x, float* __restrict__ cpy,
    us* __restrict__ hi, us* __restrict__ lo, int n8, float* __restrict__ zbuf,
    const float* __restrict__ bk, const float* __restrict__ bv,
    float* __restrict__ bkv,
    const float* __restrict__ b_in, const float* __restrict__ Wq,
    const float* __restrict__ bq, float* __restrict__ bq_eff, TSB a)
{
    __shared__ float tile[32][33];
    const int blk = blockIdx.x, tid = threadIdx.x;
    if (blk >= 2062) {            // weight transpose+split
        const int t = blk - 2062;
        const int wsel = t >> 8;
        const int n0 = (t & 15) * 32, k0 = ((t >> 4) & 15) * 32;
        const int ncols = a.nc[wsel];
        if (n0 >= ncols) return;
        const float* W = a.src[wsel];
        {
            const int r = tid >> 3, c = (tid & 7) * 4;
            const float4 v = *(const float4*)(W + (size_t)(k0 + r) * ncols + n0 + c);
            tile[r][c + 0] = v.x; tile[r][c + 1] = v.y;
            tile[r][c + 2] = v.z; tile[r][c + 3] = v.w;
        }
        __syncthreads();
        {
            const int n = tid >> 3, k = (tid & 7) * 4;
            uint2 hp, lp;
            split_pack4(tile[k + 0][n], tile[k + 1][n], tile[k + 2][n], tile[k + 3][n], hp, lp);
            *(uint2*)(a.dh[wsel] + (size_t)(n0 + n) * 512 + k0 + k) = hp;
            *(uint2*)(a.dl[wsel] + (size_t)(n0 + n) * 512 + k0 + k) = lp;
        }
        return;
    }
    if (blk >= 2060) {            // bq_eff
        const int n = (blk - 2060) * 256 + tid;
        float v = bq[n];
        for (int k = 0; k < 512; ++k) v = fmaf(b_in[k], Wq[(size_t)k * 512 + n], v);
        bq_eff[n] = v;
        return;
    }
    if (blk >= 2056) {            // bkv concat
        const int i = (blk - 2056) * 256 + tid;
        bkv[i] = (i < 512) ? bk[i] : bv[i - 512];
        return;
    }
    if (blk >= 2048) {            // zero rowmeanv
        const int i = (blk - 2048) * 2048 + tid * 8;
        *(float4*)(zbuf + i) = make_float4(0.f, 0.f, 0.f, 0.f);
        *(float4*)(zbuf + i + 4) = make_float4(0.f, 0.f, 0.f, 0.f);
        return;
    }
    const int stride = 2048 * 256;
    for (int i = blk * 256 + tid; i < n8; i += stride) {
        const float4 va = *(const float4*)(x + (size_t)i * 8);
        const float4 vb = *(const float4*)(x + (size_t)i * 8 + 4);
        *(float4*)(cpy + (size_t)i * 8) = va;
        *(float4*)(cpy + (size_t)i * 8 + 4) = vb;
        uint2 h0, l0, h1, l1;
        split_pack4(va.x, va.y, va.z, va.w, h0, l0);
        split_pack4(vb.x, vb.y, vb.z, vb.w, h1, l1);
        *(uint2*)(hi + (size_t)i * 8) = h0;
        *(uint2*)(hi + (size_t)i * 8 + 4) = h1;
        *(uint2*)(lo + (size_t)i * 8) = l0;
        *(uint2*)(lo + (size_t)i * 8 + 4) = l1;
    }
}

// ---------------------------------------------------------------------------
// split-bf16 MFMA GEMM body, f32 A split in-kernel (info + winq)
// ---------------------------------------------------------------------------
#define GEMM_F32A_BODY(K_)                                                          \
    f32x4 acc[4][4];                                                                \
    _Pragma("unroll")                                                               \
    for (int i = 0; i < 4; ++i)                                                     \
        _Pragma("unroll")                                                           \
        for (int j = 0; j < 4; ++j)                                                 \
            _Pragma("unroll")                                                       \
            for (int r = 0; r < 4; ++r) acc[i][j][r] = 0.f;                         \
    const int ar = tid >> 4;                                                        \
    const int ak = (tid & 15) * 4;                                                  \
    int bsrow[4], bsf[4], bsoff[4];                                                 \
    _Pragma("unroll")                                                               \
    for (int it = 0; it < 4; ++it) {                                                \
        const int s = tid + 256 * it;                                               \
        bsrow[it] = s >> 3;                                                         \
        bsf[it] = s & 7;                                                            \
        bsoff[it] = bsrow[it] * 64 + ((bsf[it] ^ (bsrow[it] & 7)) << 3);            \
    }                                                                               \
    for (int k0 = 0; k0 < (K_); k0 += 64) {                                         \
        __syncthreads();                                                            \
        _Pragma("unroll")                                                           \
        for (int p = 0; p < 8; ++p) {                                               \
            const int r = p * 16 + ar;                                              \
            const float4 av = *(const float4*)(A + (size_t)(m0 + r) * (K_) + k0 + ak); \
            const int aoff = r * 128 + (((ak >> 3) ^ (r & 7)) << 4) + ((tid & 1) << 3); \
            uint2 hp, lp;                                                           \
            split_pack4(av.x, av.y, av.z, av.w, hp, lp);                            \
            *(uint2*)((char*)sAh + aoff) = hp;                                      \
            *(uint2*)((char*)sAl + aoff) = lp;                                      \
        }                                                                           \
        _Pragma("unroll")                                                           \
        for (int it = 0; it < 4; ++it) {                                            \
            const size_t bo = (size_t)(n0 + bsrow[it]) * (K_) + k0 + bsf[it] * 8;   \
            *(uint4*)(sBh + bsoff[it]) = *(const uint4*)(Bh + bo);                  \
            *(uint4*)(sBl + bsoff[it]) = *(const uint4*)(Bl + bo);                  \
        }                                                                           \
        __syncthreads();                                                            \
        _Pragma("unroll")                                                           \
        for (int ks = 0; ks < 2; ++ks) {                                            \
            short8 afh[4], afl[4], bfh[4], bfl[4];                                  \
            _Pragma("unroll")                                                       \
            for (int i = 0; i < 4; ++i) {                                           \
                const int row = wm * 64 + i * 16 + fr;                              \
                const int off = row * 128 + (((ks * 4 + fq4) ^ (row & 7)) << 4);    \
                afh[i] = *(const short8*)((const char*)sAh + off);                  \
                afl[i] = *(const short8*)((const char*)sAl + off);                  \
            }                                                                       \
            _Pragma("unroll")                                                       \
            for (int j = 0; j < 4; ++j) {                                           \
                const int row = wn * 64 + j * 16 + fr;                              \
                const int off = row * 128 + (((ks * 4 + fq4) ^ (row & 7)) << 4);    \
                bfh[j] = *(const short8*)((const char*)sBh + off);                  \
                bfl[j] = *(const short8*)((const char*)sBl + off);                  \
            }                                                                       \
            _Pragma("unroll")                                                       \
            for (int i = 0; i < 4; ++i)                                             \
                _Pragma("unroll")                                                   \
                for (int j = 0; j < 4; ++j) {                                       \
                    acc[i][j] = __builtin_amdgcn_mfma_f32_16x16x32_bf16(afh[i], bfh[j], acc[i][j], 0, 0, 0); \
                    acc[i][j] = __builtin_amdgcn_mfma_f32_16x16x32_bf16(afh[i], bfl[j], acc[i][j], 0, 0, 0); \
                    acc[i][j] = __builtin_amdgcn_mfma_f32_16x16x32_bf16(afl[i], bfh[j], acc[i][j], 0, 0, 0); \
                }                                                                   \
        }                                                                           \
    }

// ---------------------------------------------------------------------------
// MERGED info-GEMM + winq-GEMM (272 blocks):
//  id<256: info_proj = new_info@W_in + b_in -> pre-split hi/lo
//  id>=256: winq = W_in@Wq -> written TRANSPOSED+SPLIT (wtinq), no f32 buffer
// ---------------------------------------------------------------------------
__global__ __launch_bounds__(256) void gemm_info_winq(
    const float* __restrict__ new_info,
    const us* __restrict__ wtin_h, const us* __restrict__ wtin_l,
    const float* __restrict__ b_in,
    us* __restrict__ Oh, us* __restrict__ Ol,
    const float* __restrict__ W_in,
    const us* __restrict__ wtq_h, const us* __restrict__ wtq_l,
    us* __restrict__ wtinq_h, us* __restrict__ wtinq_l)
{
    __shared__ us sm[32768];
    us* sAh = sm;            us* sAl = sm + 8192;
    us* sBh = sm + 16384;    us* sBl = sm + 24576;
    const int tid = threadIdx.x, lane = tid & 63;
    const int wid = tid >> 6, wm = wid >> 1, wn = wid & 1;
    const int fr = lane & 15, fq4 = lane >> 4;
    const int id = blockIdx.x;
    const bool isInfo = (id < 256);
    int m0, n0;
    const float* A;
    const us *Bh, *Bl;
    if (isInfo) {
        m0 = (id >> 2) * 128; n0 = (id & 3) * 128;
        A = new_info; Bh = wtin_h; Bl = wtin_l;
    } else {
        const int t = id - 256;
        m0 = (t >> 2) * 128; n0 = (t & 3) * 128;
        A = W_in; Bh = wtq_h; Bl = wtq_l;
    }
    GEMM_F32A_BODY(512)

    if (isInfo) {
#pragma unroll
        for (int j = 0; j < 4; ++j) {
            const int col = n0 + wn * 64 + j * 16 + fr;
            const float bj = b_in[col];
#pragma unroll
            for (int i = 0; i < 4; ++i)
#pragma unroll
                for (int r = 0; r < 4; ++r) {
                    const int row = m0 + wm * 64 + i * 16 + fq4 * 4 + r;
                    const float v = acc[i][j][r] + bj;
                    const us hv = bf_hi(v);
                    Oh[(size_t)row * 512 + col] = hv;
                    Ol[(size_t)row * 512 + col] = bf_hi(v - bf_f(hv));
                }
        }
    } else {
        // winq[k][n]; emit transposed: wtinq[n][k]
#pragma unroll
        for (int j = 0; j < 4; ++j) {
            const int col = n0 + wn * 64 + j * 16 + fr;
#pragma unroll
            for (int i = 0; i < 4; ++i)
#pragma unroll
                for (int r = 0; r < 4; ++r) {
                    const int row = m0 + wm * 64 + i * 16 + fq4 * 4 + r;  // k
                    const float v = acc[i][j][r];
                    const us hv = bf_hi(v);
                    wtinq_h[(size_t)col * 512 + row] = hv;
                    wtinq_l[(size_t)col * 512 + row] = bf_hi(v - bf_f(hv));
                }
        }
    }
}

// ---------------------------------------------------------------------------
// PRE-SPLIT MFMA GEMM core (R9-validated DMA staging)
// ---------------------------------------------------------------------------
#define GEMM_PS_CORE(AhP, AlP, BhP, BlP, rsA_, K_)                                  \
    us* sAh = sm;            us* sAl = sm + 8192;                                   \
    us* sBh = sm + 16384;    us* sBl = sm + 24576;                                  \
    f32x4 acc[4][4];                                                                \
    _Pragma("unroll")                                                               \
    for (int i = 0; i < 4; ++i)                                                     \
        _Pragma("unroll")                                                           \
        for (int j = 0; j < 4; ++j)                                                 \
            _Pragma("unroll")                                                       \
            for (int r = 0; r < 4; ++r) acc[i][j][r] = 0.f;                         \
    const int fp = lane & 7, rsub = lane >> 3;                                      \
    const us* gsrc = (wid == 0) ? (AhP) : (wid == 1) ? (AlP)                        \
                   : (wid == 2) ? (BhP) : (BlP);                                    \
    const int grow0 = (wid < 2) ? m0 : n0;                                          \
    const int grs = (wid < 2) ? (rsA_) : (K_);                                      \
    us* lbase = sm + wid * 8192;                                                    \
    for (int k0 = 0; k0 < (K_); k0 += 64) {                                         \
        __syncthreads();                                                            \
        _Pragma("unroll")                                                           \
        for (int i = 0; i < 16; ++i) {                                              \
            const int row = i * 8 + rsub;                                           \
            const us* g = gsrc + (size_t)(grow0 + row) * grs + k0 +                 \
                          ((fp ^ (row & 7)) << 3);                                  \
            gload_lds16(g, lbase + i * 512);                                        \
        }                                                                           \
        __syncthreads();                                                            \
        _Pragma("unroll")                                                           \
        for (int ks = 0; ks < 2; ++ks) {                                            \
            short8 afh[4], afl[4], bfh[4], bfl[4];                                  \
            _Pragma("unroll")                                                       \
            for (int i = 0; i < 4; ++i) {                                           \
                const int row = wm * 64 + i * 16 + fr;                              \
                const int off = row * 128 + (((ks * 4 + fq4) ^ (row & 7)) << 4);    \
                afh[i] = *(const short8*)((const char*)sAh + off);                  \
                afl[i] = *(const short8*)((const char*)sAl + off);                  \
            }                                                                       \
            _Pragma("unroll")                                                       \
            for (int j = 0; j < 4; ++j) {                                           \
                const int row = wn * 64 + j * 16 + fr;                              \
                const int off = row * 128 + (((ks * 4 + fq4) ^ (row & 7)) << 4);    \
                bfh[j] = *(const short8*)((const char*)sBh + off);                  \
                bfl[j] = *(const short8*)((const char*)sBl + off);                  \
            }                                                                       \
            _Pragma("unroll")                                                       \
            for (int i = 0; i < 4; ++i)                                             \
                _Pragma("unroll")                                                   \
                for (int j = 0; j < 4; ++j) {                                       \
                    acc[i][j] = __builtin_amdgcn_mfma_f32_16x16x32_bf16(afh[i], bfh[j], acc[i][j], 0, 0, 0); \
                    acc[i][j] = __builtin_amdgcn_mfma_f32_16x16x32_bf16(afh[i], bfl[j], acc[i][j], 0, 0, 0); \
                    acc[i][j] = __builtin_amdgcn_mfma_f32_16x16x32_bf16(afl[i], bfh[j], acc[i][j], 0, 0, 0); \
                }                                                                   \
        }                                                                           \
    }

// hidden1 = relu(info_proj@Wi1 + bi1), f32 out; N=256, grid (2,64)
__global__ __launch_bounds__(256) void gemm_h1_ps(
    const us* __restrict__ Ah, const us* __restrict__ Al,
    const us* __restrict__ Bh, const us* __restrict__ Bl,
    const float* __restrict__ bias, float* __restrict__ C)
{
    __shared__ us sm[32768];
    const int tid = threadIdx.x, lane = tid & 63;
    const int wid = tid >> 6, wm = wid >> 1, wn = wid & 1;
    const int fr = lane & 15, fq4 = lane >> 4;
    const int m0 = blockIdx.y * 128, n0 = blockIdx.x * 128;
    GEMM_PS_CORE(Ah, Al, Bh, Bl, 512, 512)
#pragma unroll
    for (int j = 0; j < 4; ++j) {
        const int col = n0 + wn * 64 + j * 16 + fr;
        const float bj = bias[col];
#pragma unroll
        for (int i = 0; i < 4; ++i)
#pragma unroll
            for (int r = 0; r < 4; ++r) {
                const int row = m0 + wm * 64 + i * 16 + fq4 * 4 + r;
                C[(size_t)row * 256 + col] = fmaxf(acc[i][j][r] + bj, 0.f);
            }
    }
}

// ---------------------------------------------------------------------------
// MERGED imp + impstats: 8 blocks (one per batch)
// ---------------------------------------------------------------------------
__global__ __launch_bounds__(256) void imp_all(
    const float* __restrict__ h1, const float* __restrict__ Wi2,
    const float* __restrict__ bi2, float* __restrict__ imp,
    float* __restrict__ imp_mean, int* __restrict__ s_star,
    int* __restrict__ exists)
{
    const int b = blockIdx.x, w = threadIdx.x >> 6, lane = threadIdx.x & 63;
    const float4 wv = *(const float4*)(Wi2 + lane * 4);
    const float b0 = bi2[0];
    float sum = 0.f; int last = -1;
    for (int i = 0; i < 256; ++i) {
        const int row = b * 1024 + w + i * 4;
        const float4 hv = *(const float4*)(h1 + (size_t)row * 256 + lane * 4);
        float s = hv.x * wv.x + hv.y * wv.y + hv.z * wv.z + hv.w * wv.w;
#pragma unroll
        for (int m = 1; m < 64; m <<= 1) s += __shfl_xor(s, m);
        const float ip = 1.0f / (1.0f + expf(-(s + b0)));
        if (lane == 0) {
            imp[row] = ip;
            sum += ip;
            if (ip > 0.5f) last = row;
        }
    }
    __shared__ float ssum[4]; __shared__ int slast[4];
    if (lane == 0) { ssum[w] = sum; slast[w] = last; }
    __syncthreads();
    if (threadIdx.x == 0) {
        const float t = ssum[0] + ssum[1] + ssum[2] + ssum[3];
        const int ml = max(max(slast[0], slast[1]), max(slast[2], slast[3]));
        imp_mean[b] = t / (float)SS;
        exists[b] = (ml >= 0) ? 1 : 0;
        s_star[b] = (ml >= 0) ? (ml - b * 1024) : (SS - 1);
    }
}

// ---------------------------------------------------------------------------
// merged Q-GEMM + KV-GEMM: 1024 blocks. Q output PRE-SPLIT (qsph/qspl);
// K output pre-scaled by 1/8 (moves the 1/sqrt(d) off attn's Q path).
// ---------------------------------------------------------------------------
__global__ __launch_bounds__(256) void gemm_qkv_ps(
    const us* __restrict__ mbh, const us* __restrict__ mbl,
    const us* __restrict__ wtinq_h, const us* __restrict__ wtinq_l,
    const float* __restrict__ bq_eff,
    us* __restrict__ qsph, us* __restrict__ qspl,
    const us* __restrict__ iph, const us* __restrict__ ipl,
    const us* __restrict__ wtkv_h, const us* __restrict__ wtkv_l,
    const float* __restrict__ bkv,
    us* __restrict__ Kh, us* __restrict__ Kl,
    us* __restrict__ Vth, us* __restrict__ Vtl)
{
    __shared__ us sm[32768];
    const int tid = threadIdx.x, lane = tid & 63;
    const int wid = tid >> 6, wm = wid >> 1, wn = wid & 1;
    const int fr = lane & 15, fq4 = lane >> 4;
    const int id = blockIdx.x;
    const bool isQ = (id < 512);
    int m0, n0;
    const us *Ah, *Al, *Bh, *Bl;
    if (isQ) {
        m0 = (id >> 2) * 128; n0 = (id & 3) * 128;
        Ah = mbh; Al = mbl; Bh = wtinq_h; Bl = wtinq_l;
    } else {
        const int t = id - 512;
        m0 = (t >> 3) * 128; n0 = (t & 7) * 128;
        Ah = iph; Al = ipl; Bh = wtkv_h; Bl = wtkv_l;
    }
    GEMM_PS_CORE(Ah, Al, Bh, Bl, 512, 512)

    if (isQ) {
#pragma unroll
        for (int j = 0; j < 4; ++j) {
            const int col = n0 + wn * 64 + j * 16 + fr;
            const float bj = bq_eff[col];
#pragma unroll
            for (int i = 0; i < 4; ++i)
#pragma unroll
                for (int r = 0; r < 4; ++r) {
                    const int row = m0 + wm * 64 + i * 16 + fq4 * 4 + r;
                    const float v = acc[i][j][r] + bj;
                    const us hv = bf_hi(v);
                    qsph[(size_t)row * 512 + col] = hv;
                    qspl[(size_t)row * 512 + col] = bf_hi(v - bf_f(hv));
                }
        }
    } else if (n0 < 512) {
#pragma unroll
        for (int j = 0; j < 4; ++j) {
            const int col = n0 + wn * 64 + j * 16 + fr;
            const float bj = bkv[col];
#pragma unroll
            for (int i = 0; i < 4; ++i)
#pragma unroll
                for (int r = 0; r < 4; ++r) {
                    const int row = m0 + wm * 64 + i * 16 + fq4 * 4 + r;
                    const float v = (acc[i][j][r] + bj) * 0.125f;  // 1/sqrt(64)
                    const us hv = bf_hi(v);
                    Kh[(size_t)row * 512 + col] = hv;
                    Kl[(size_t)row * 512 + col] = bf_hi(v - bf_f(hv));
                }
        }
    } else {
#pragma unroll
        for (int j = 0; j < 4; ++j) {
            const int col = n0 + wn * 64 + j * 16 + fr;
            const float bj = bkv[col];
            const int d = col - 512;
#pragma unroll
            for (int i = 0; i < 4; ++i) {
                const int row0 = m0 + wm * 64 + i * 16 + fq4 * 4;
                uint2 hp, lp;
                split_pack4(acc[i][j][0] + bj, acc[i][j][1] + bj,
                            acc[i][j][2] + bj, acc[i][j][3] + bj, hp, lp);
                const size_t vo = ((size_t)(row0 >> 10) * 512 + d) * 1024 + (row0 & 1023);
                *(uint2*)(Vth + vo) = hp;
                *(uint2*)(Vtl + vo) = lp;
            }
        }
    }
}

// Wo-GEMM with fused rowmean
__global__ __launch_bounds__(256) void gemm_wo_ps(
    const us* __restrict__ Ah, const us* __restrict__ Al,
    const us* __restrict__ Bh, const us* __restrict__ Bl,
    const float* __restrict__ bias, float* __restrict__ C,
    const float* __restrict__ rowscale, float* __restrict__ rowmeanv)
{
    __shared__ us sm[32768];
    const int tid = threadIdx.x, lane = tid & 63;
    const int wid = tid >> 6, wm = wid >> 1, wn = wid & 1;
    const int fr = lane & 15, fq4 = lane >> 4;
    const int m0 = blockIdx.y * 128, n0 = blockIdx.x * 128;
    GEMM_PS_CORE(Ah, Al, Bh, Bl, 512, 512)

    float rsum[4][4];
#pragma unroll
    for (int i = 0; i < 4; ++i)
#pragma unroll
        for (int r = 0; r < 4; ++r) rsum[i][r] = 0.f;

#pragma unroll
    for (int j = 0; j < 4; ++j) {
        const int col = n0 + wn * 64 + j * 16 + fr;
        const float bj = bias[col];
#pragma unroll
        for (int i = 0; i < 4; ++i)
#pragma unroll
            for (int r = 0; r < 4; ++r) {
                const int row = m0 + wm * 64 + i * 16 + fq4 * 4 + r;
                const float v = (acc[i][j][r] + bj) * rowscale[row / MM];
                C[(size_t)row * 512 + col] = v;
                rsum[i][r] += v;
            }
    }

    __syncthreads();
    float* red = (float*)sm;
    if (tid < 128) red[tid] = 0.f;
    __syncthreads();
#pragma unroll
    for (int i = 0; i < 4; ++i)
#pragma unroll
        for (int r = 0; r < 4; ++r)
            atomicAdd(&red[wm * 64 + i * 16 + fq4 * 4 + r], rsum[i][r]);
    __syncthreads();
    if (tid < 128) atomicAdd(&rowmeanv[m0 + tid], red[tid] * (1.0f / 512.0f));
}

// ---------------------------------------------------------------------------
// MFMA flash attention: DMA-staged K/V, pre-split Q (no split VALU on load),
// defer-max skip (bit-identical: scf==1 when max doesn't grow).
// Epilogue emits pre-split hi/lo into mbh/mbl (dead after Q-GEMM).
// ---------------------------------------------------------------------------
__global__ __launch_bounds__(256) void attn_mfma(
    const us* __restrict__ Qh, const us* __restrict__ Ql,
    const us* __restrict__ Kh, const us* __restrict__ Kl,
    const us* __restrict__ Vth, const us* __restrict__ Vtl,
    us* __restrict__ aoh, us* __restrict__ aol)
{
    __shared__ us sm[24576];
    __shared__ float sSc[64];
    us* sKh = sm;            us* sKl = sm + 4096;
    us* sVh = sm + 8192;     us* sVl = sm + 12288;
    us* sPh = sm + 16384;    us* sPl = sm + 20480;

    const int tid = threadIdx.x, lane = tid & 63, w = tid >> 6;
    const int fr = lane & 15, fq4 = lane >> 4;

    const int wg = blockIdx.x;
    const int xcd = wg & 7, ix = wg >> 3;
    const int mt = ix & 31;
    const int pair = xcd + 8 * (ix >> 5);
    const int h = pair & 7, b = pair >> 3;
    const int m0 = mt * 64;

    const us* Qgh = Qh + ((size_t)(b * MM + m0)) * 512 + h * DHEAD;
    const us* Qgl = Ql + ((size_t)(b * MM + m0)) * 512 + h * DHEAD;
    const us* Kgh = Kh + ((size_t)b * SS) * 512 + h * DHEAD;
    const us* Kgl = Kl + ((size_t)b * SS) * 512 + h * DHEAD;
    const us* Vgh = Vth + ((size_t)b * 512 + h * DHEAD) * 1024;
    const us* Vgl = Vtl + ((size_t)b * 512 + h * DHEAD) * 1024;
    us* Oh = aoh + ((size_t)(b * MM + m0)) * 512 + h * DHEAD;
    us* Ol = aol + ((size_t)(b * MM + m0)) * 512 + h * DHEAD;

    // ---- Q fragments: direct pre-split loads (scale lives in K)
    short8 qfh[2], qfl[2];
#pragma unroll
    for (int ks = 0; ks < 2; ++ks) {
        const size_t qo = (size_t)(w * 16 + fr) * 512 + ks * 32 + fq4 * 8;
        qfh[ks] = *(const short8*)(Qgh + qo);
        qfl[ks] = *(const short8*)(Qgl + qo);
    }

    const int fp = lane & 7;
    const int rsub = lane >> 3;
    const bool isK = (w < 2);
    const us* gA = (w == 0) ? Kgh : (w == 1) ? Kgl : (w == 2) ? Vgh : Vgl;
    us* lbase = sm + w * 4096;

    f32x4 oacc[4];
#pragma unroll
    for (int j = 0; j < 4; ++j)
#pragma unroll
        for (int r = 0; r < 4; ++r) oacc[j][r] = 0.f;
    float mrun = -1e30f, lrun = 0.f;

    for (int t = 0; t < SS / 64; ++t) {
        __syncthreads();
        if (isK) {
#pragma unroll
            for (int i = 0; i < 8; ++i) {
                const int row = i * 8 + rsub;
                const us* g = gA + (size_t)(t * 64 + row) * 512 + ((fp ^ (row & 7)) << 3);
                gload_lds16(g, lbase + i * 512);
            }
        } else {
#pragma unroll
            for (int i = 0; i < 8; ++i) {
                const int row = i * 8 + rsub;
                const us* g = gA + (size_t)row * 1024 + t * 64 + ((fp ^ (row & 7)) << 3);
                gload_lds16(g, lbase + i * 512);
            }
        }
        __syncthreads();

        f32x4 stt[4];
#pragma unroll
        for (int fs = 0; fs < 4; ++fs)
#pragma unroll
            for (int r = 0; r < 4; ++r) stt[fs][r] = 0.f;
#pragma unroll
        for (int ks = 0; ks < 2; ++ks) {
            short8 kfh[4], kfl[4];
#pragma unroll
            for (int fs = 0; fs < 4; ++fs) {
                const int row = fs * 16 + fr;
                const int off = row * 128 + (((ks * 4 + fq4) ^ (row & 7)) << 4);
                kfh[fs] = *(const short8*)((const char*)sKh + off);
                kfl[fs] = *(const short8*)((const char*)sKl + off);
            }
#pragma unroll
            for (int fs = 0; fs < 4; ++fs) {
                stt[fs] = __builtin_amdgcn_mfma_f32_16x16x32_bf16(kfh[fs], qfh[ks], stt[fs], 0, 0, 0);
                stt[fs] = __builtin_amdgcn_mfma_f32_16x16x32_bf16(kfh[fs], qfl[ks], stt[fs], 0, 0, 0);
                stt[fs] = __builtin_amdgcn_mfma_f32_16x16x32_bf16(kfl[fs], qfh[ks], stt[fs], 0, 0, 0);
            }
        }

        // ---- online softmax with defer-max (wave-uniform skip; bit-identical)
        float mx = stt[0][0];
#pragma unroll
        for (int fs = 0; fs < 4; ++fs)
#pragma unroll
            for (int r = 0; r < 4; ++r) mx = fmaxf(mx, stt[fs][r]);
        mx = fmaxf(mx, __shfl_xor(mx, 16));
        mx = fmaxf(mx, __shfl_xor(mx, 32));
        const bool grow = __any(mx > mrun);
        float scf = 1.f;
        if (grow) {
            const float nm = fmaxf(mrun, mx);
            scf = __expf(mrun - nm);
            mrun = nm;
            if (fq4 == 0) sSc[w * 16 + fr] = scf;
        }
        float ps = 0.f;
#pragma unroll
        for (int fs = 0; fs < 4; ++fs)
#pragma unroll
            for (int r = 0; r < 4; ++r) {
                const float p = __expf(stt[fs][r] - mrun);
                stt[fs][r] = p;
                ps += p;
            }
        ps += __shfl_xor(ps, 16);
        ps += __shfl_xor(ps, 32);
        lrun = lrun * scf + ps;

        // ---- write P[q][s] hi/lo (wave-private rows)
#pragma unroll
        for (int fs = 0; fs < 4; ++fs) {
            const int q = w * 16 + fr;
            const int flog = (fs << 1) | (fq4 >> 1);
            const int off = q * 128 + ((flog ^ (q & 7)) << 4) + ((fq4 & 1) << 3);
            uint2 hp, lp;
            split_pack4(stt[fs][0], stt[fs][1], stt[fs][2], stt[fs][3], hp, lp);
            *(uint2*)((char*)sPh + off) = hp;
            *(uint2*)((char*)sPl + off) = lp;
        }

        // ---- rescale oacc only when a max grew
        if (grow) {
#pragma unroll
            for (int r = 0; r < 4; ++r) {
                const float scv = sSc[w * 16 + fq4 * 4 + r];
#pragma unroll
                for (int fd = 0; fd < 4; ++fd) oacc[fd][r] *= scv;
            }
        }

        // ---- PV
#pragma unroll
        for (int ks = 0; ks < 2; ++ks) {
            short8 pfh, pfl, vfh[4], vfl[4];
            {
                const int row = w * 16 + fr;
                const int off = row * 128 + (((ks * 4 + fq4) ^ (row & 7)) << 4);
                pfh = *(const short8*)((const char*)sPh + off);
                pfl = *(const short8*)((const char*)sPl + off);
            }
#pragma unroll
            for (int fd = 0; fd < 4; ++fd) {
                const int row = fd * 16 + fr;
                const int off = row * 128 + (((ks * 4 + fq4) ^ (row & 7)) << 4);
                vfh[fd] = *(const short8*)((const char*)sVh + off);
                vfl[fd] = *(const short8*)((const char*)sVl + off);
            }
#pragma unroll
            for (int fd = 0; fd < 4; ++fd) {
                oacc[fd] = __builtin_amdgcn_mfma_f32_16x16x32_bf16(pfh, vfh[fd], oacc[fd], 0, 0, 0);
                oacc[fd] = __builtin_amdgcn_mfma_f32_16x16x32_bf16(pfh, vfl[fd], oacc[fd], 0, 0, 0);
                oacc[fd] = __builtin_amdgcn_mfma_f32_16x16x32_bf16(pfl, vfh[fd], oacc[fd], 0, 0, 0);
            }
        }
    }

    // ---- normalize + store pre-split
    if (fq4 == 0) sSc[w * 16 + fr] = lrun;
#pragma unroll
    for (int r = 0; r < 4; ++r) {
        const float inv = 1.0f / sSc[w * 16 + fq4 * 4 + r];
        const int q = w * 16 + fq4 * 4 + r;
#pragma unroll
        for (int fd = 0; fd < 4; ++fd) {
            const float v = oacc[fd][r] * inv;
            const us hv = bf_hi(v);
            Oh[(size_t)q * 512 + fd * 16 + fr] = hv;
            Ol[(size_t)q * 512 + fd * 16 + fr] = bf_hi(v - bf_f(hv));
        }
    }
}

// ---------------------------------------------------------------------------
// MERGED argmax + update: 8 blocks; argmax -> LDS pos -> update MLP
// ---------------------------------------------------------------------------
__global__ __launch_bounds__(256) void argmax_update(
    const float* __restrict__ rm,
    const float* __restrict__ mb, const float* __restrict__ ni,
    const float* __restrict__ Wu1, const float* __restrict__ bu1,
    const float* __restrict__ Wu2, const float* __restrict__ bu2,
    const float* __restrict__ wwp, const int* __restrict__ s_star,
    const int* __restrict__ exists, float* __restrict__ outu)
{
    const int b = blockIdx.x, tid = threadIdx.x;
    __shared__ float comb[2 * DD];
    __shared__ float hu[HH];
    __shared__ float sv[4]; __shared__ int si[4];
    __shared__ int spos;

    // ---- phase 1: first-occurrence argmax over M rowmeans
    {
        float best = -3.0e38f; int bidx = 1 << 30;
        for (int m = tid; m < MM; m += 256) {
            const float v = rm[b * MM + m];
            if (v > best || (v == best && m < bidx)) { best = v; bidx = m; }
        }
#pragma unroll
        for (int msk = 1; msk < 64; msk <<= 1) {
            const float ov = __shfl_xor(best, msk);
            const int oi = __shfl_xor(bidx, msk);
            if (ov > best || (ov == best && oi < bidx)) { best = ov; bidx = oi; }
        }
        if ((tid & 63) == 0) { sv[tid >> 6] = best; si[tid >> 6] = bidx; }
        __syncthreads();
        if (tid == 0) {
            for (int w = 1; w < 4; ++w)
                if (sv[w] > best || (sv[w] == best && si[w] < bidx)) { best = sv[w]; bidx = si[w]; }
            spos = bidx;
        }
        __syncthreads();
    }

    // ---- phase 2: update MLP on the selected row
    const int p = spos, ss = s_star[b], ex = exists[b];
    const float* oldp = mb + ((size_t)(b * MM + p)) * DD;
    const float* selp = ni + ((size_t)(b * SS + ss)) * DD;
    for (int i = tid; i < DD; i += 256) { comb[i] = oldp[i]; comb[DD + i] = selp[i]; }
    __syncthreads();
#pragma unroll
    for (int t = 0; t < 2; ++t) {
        const int n = tid + t * 256;
        float a = bu1[n];
        for (int k = 0; k < 2 * DD; ++k) a = fmaf(comb[k], Wu1[(size_t)k * HH + n], a);
        hu[n] = fmaxf(a, 0.f);
    }
    __syncthreads();
#pragma unroll
    for (int t = 0; t < 2; ++t) {
        const int n = tid + t * 256;
        float a = bu2[n];
        for (int k = 0; k < HH; ++k) a = fmaf(hu[k], Wu2[(size_t)k * HH + n], a);
        const float upd = tanhf(a);
        const float wwv = wwp[((size_t)(b * MM + p)) * HH + n];
        const float ov = oldp[n];
        outu[((size_t)(b * MM + p)) * DD + n] = ex ? fmaf(upd, wwv, ov) : ov;
    }
}

extern "C" void kernel_launch(void* const* d_in, const int* in_sizes, int n_in,
                              void* d_out, int out_size, void* d_ws, size_t ws_size,
                              hipStream_t stream)
{
    const float* new_info    = (const float*)d_in[0];
    const float* memory_bank = (const float*)d_in[1];
    const float* W_in = (const float*)d_in[2];  const float* b_in = (const float*)d_in[3];
    const float* Wq   = (const float*)d_in[4];  const float* bq   = (const float*)d_in[5];
    const float* Wk   = (const float*)d_in[6];  const float* bk   = (const float*)d_in[7];
    const float* Wv   = (const float*)d_in[8];  const float* bv   = (const float*)d_in[9];
    const float* Wo   = (const float*)d_in[10]; const float* bo   = (const float*)d_in[11];
    const float* Wi1  = (const float*)d_in[12]; const float* bi1  = (const float*)d_in[13];
    const float* Wi2  = (const float*)d_in[14]; const float* bi2  = (const float*)d_in[15];
    const float* Wu1  = (const float*)d_in[16]; const float* bu1  = (const float*)d_in[17];
    const float* Wu2  = (const float*)d_in[18]; const float* bu2  = (const float*)d_in[19];

    float* out = (float*)d_out;
    float* out_updated = out;                               // B*M*D
    float* out_ww      = out + (size_t)BB * MM * HH;        // B*M*H
    float* out_imp     = out + 2 * (size_t)BB * MM * HH;    // B*S

    // workspace layout (f32 units), ~125 MB
    float* ws = (float*)d_ws;
    float* qsp_rg    = ws;                                  // 8,388,608 (qsph/qspl; hidden1 aliases)
    float* ip_sp     = qsp_rg + 8388608;                    // 4,194,304 (iph/ipl)
    float* mb_sp     = ip_sp + 4194304;                     // 8,388,608 (mbh/mbl; attn out reuses)
    float* kvreg     = mb_sp + 8388608;                     // 8,388,608 (K/V splits)
    float* wtf       = kvreg + 8388608;                     // 1,703,936 (us pairs)
    float* bq_eff    = wtf + 1703936;                       // 512
    float* bkv       = bq_eff + 512;                        // 1024
    float* rowmeanv  = bkv + 1024;                          // 16,384
    float* imp_mean  = rowmeanv + 16384;                    // 8
    int*   istar     = (int*)(imp_mean + BB);
    int*   iexists   = istar + BB;

    float* hidden1 = qsp_rg;  // B*S*256 f32, dead before Q-GEMM writes qsp

    us* qsph = (us*)qsp_rg;        // [16384][512]
    us* qspl = qsph + 8388608;
    us* iph = (us*)ip_sp;          // [8192][512]
    us* ipl = iph + 4194304;
    us* mbh = (us*)mb_sp;          // [16384][512]
    us* mbl = mbh + 8388608;
    us* Kh  = (us*)kvreg;          // [8192][512]
    us* Kl  = Kh + 4194304;
    us* Vth = Kl + 4194304;        // [8][512][1024]
    us* Vtl = Vth + 4194304;

    us* wtin_h  = (us*)wtf;            us* wtin_l  = wtin_h + 262144;
    us* wtq_h   = wtin_l + 262144;     us* wtq_l   = wtq_h + 262144;
    us* wtkv_h  = wtq_l + 262144;      us* wtkv_l  = wtkv_h + 524288;   // [1024][512]
    us* wto_h   = wtkv_l + 524288;     us* wto_l   = wto_h + 262144;
    us* wtinq_h = wto_l + 262144;      us* wtinq_l = wtinq_h + 262144;
    us* wti1_h  = wtinq_l + 262144;    us* wti1_l  = wti1_h + 131072;   // [256][512]

    const dim3 blk(256);

    // 1) merged prep: mb copy+split, rowmeanv zero, bkv, bq_eff, 6x transpose
    TSB ts;
    ts.src[0] = W_in; ts.dh[0] = wtin_h;          ts.dl[0] = wtin_l;          ts.nc[0] = 512;
    ts.src[1] = Wq;   ts.dh[1] = wtq_h;           ts.dl[1] = wtq_l;           ts.nc[1] = 512;
    ts.src[2] = Wk;   ts.dh[2] = wtkv_h;          ts.dl[2] = wtkv_l;          ts.nc[2] = 512;
    ts.src[3] = Wv;   ts.dh[3] = wtkv_h + 262144; ts.dl[3] = wtkv_l + 262144; ts.nc[3] = 512;
    ts.src[4] = Wo;   ts.dh[4] = wto_h;           ts.dl[4] = wto_l;           ts.nc[4] = 512;
    ts.src[5] = Wi1;  ts.dh[5] = wti1_h;          ts.dl[5] = wti1_l;          ts.nc[5] = 256;
    prep_all<<<dim3(2062 + 1536), blk, 0, stream>>>(memory_bank, out_updated,
                                                    mbh, mbl, 1048576, rowmeanv,
                                                    bk, bv, bkv, b_in, Wq, bq,
                                                    bq_eff, ts);

    // 2) merged info-GEMM (pre-split out) + winq-GEMM (transposed-split out)
    gemm_info_winq<<<dim3(272), blk, 0, stream>>>(new_info, wtin_h, wtin_l, b_in,
                                                  iph, ipl, W_in, wtq_h, wtq_l,
                                                  wtinq_h, wtinq_l);

    // 3) hidden1 = relu(info@Wi1+bi1)
    gemm_h1_ps<<<dim3(2, 64), blk, 0, stream>>>(iph, ipl, wti1_h, wti1_l,
                                                bi1, hidden1);

    // 4) merged importance sigmoid + stats
    imp_all<<<dim3(BB), blk, 0, stream>>>(hidden1, Wi2, bi2, out_imp,
                                          imp_mean, istar, iexists);

    // 5) merged Q-GEMM (pre-split out) + KV-GEMM (K pre-scaled 1/8)
    gemm_qkv_ps<<<dim3(1024), blk, 0, stream>>>(mbh, mbl, wtinq_h, wtinq_l,
                                                bq_eff, qsph, qspl,
                                                iph, ipl, wtkv_h, wtkv_l, bkv,
                                                Kh, Kl, Vth, Vtl);

    // 6) MFMA flash attention -> pre-split output into mbh/mbl (dead now)
    attn_mfma<<<dim3(2048), blk, 0, stream>>>(qsph, qspl, Kh, Kl, Vth, Vtl,
                                              mbh, mbl);

    // 7) output projection + imp_mean rowscale + fused rowmean
    gemm_wo_ps<<<dim3(4, 128), blk, 0, stream>>>(mbh, mbl, wto_h, wto_l,
                                                 bo, out_ww, imp_mean, rowmeanv);

    // 8) merged argmax + final row update
    argmax_update<<<dim3(BB), blk, 0, stream>>>(rowmeanv, memory_bank, new_info,
                                                Wu1, bu1, Wu2, bu2, out_ww,
                                                istar, iexists, out_updated);
}

// Round 14
// 446.665 us; speedup vs baseline: 1.3009x; 1.3009x over previous
//
#include <hip/hip_runtime.h>
#include <hip/hip_bf16.h>
#include <math.h>

// Problem constants (AttentionWriter): B=8,S=1024,M=2048,D=512,H=512,NH=8,Dh=64
#define BB 8
#define SS 1024
#define MM 2048
#define DD 512
#define HH 512
#define NHEAD 8
#define DHEAD 64

typedef __attribute__((ext_vector_type(8))) short short8;
typedef __attribute__((ext_vector_type(4))) float f32x4;
typedef unsigned short us;

// bf16 split helpers — native cvt (v_cvt_pk_bf16_f32), RNE
__device__ __forceinline__ us bf_hi(float x) {
    __hip_bfloat16 h = __float2bfloat16(x);
    return *reinterpret_cast<const us*>(&h);
}
__device__ __forceinline__ float bf_f(us h) {
    return __uint_as_float(((unsigned)h) << 16);
}
__device__ __forceinline__ void split_pack4(float a, float b, float c, float d,
                                            uint2& hp, uint2& lp) {
    us h0 = bf_hi(a), h1 = bf_hi(b), h2 = bf_hi(c), h3 = bf_hi(d);
    hp.x = (unsigned)h0 | ((unsigned)h1 << 16);
    hp.y = (unsigned)h2 | ((unsigned)h3 << 16);
    us l0 = bf_hi(a - bf_f(h0)), l1 = bf_hi(b - bf_f(h1));
    us l2 = bf_hi(c - bf_f(h2)), l3 = bf_hi(d - bf_f(h3));
    lp.x = (unsigned)l0 | ((unsigned)l1 << 16);
    lp.y = (unsigned)l2 | ((unsigned)l3 << 16);
}

// async global->LDS DMA, 16B per lane; LDS dest = wave-uniform base + lane*16
__device__ __forceinline__ void gload_lds16(const void* g, void* l) {
    __builtin_amdgcn_global_load_lds(
        (__attribute__((address_space(1))) void*)(g),
        (__attribute__((address_space(3))) void*)(l), 16, 0, 0);
}

struct TSB {
    const float* src[6];
    us* dh[6];
    us* dl[6];
    int nc[6];
};

// ---------------------------------------------------------------------------
// MERGED prep: [0,2048) copy+split memory_bank; [2048,2060) zero
// rowmeanv+logit (24576 floats); [2060,2064) bkv; [2064,2066) bq_eff;
// [2066,2066+1536) 6x weight transpose+split
// ---------------------------------------------------------------------------
__global__ __launch_bounds__(256) void prep_all(
    const float* __restrict__ x, float* __restrict__ cpy,
    us* __restrict__ hi, us* __restrict__ lo, int n8, float* __restrict__ zbuf,
    const float* __restrict__ bk, const float* __restrict__ bv,
    float* __restrict__ bkv,
    const float* __restrict__ b_in, const float* __restrict__ Wq,
    const float* __restrict__ bq, float* __restrict__ bq_eff, TSB a)
{
    __shared__ float tile[32][33];
    const int blk = blockIdx.x, tid = threadIdx.x;
    if (blk >= 2066) {            // weight transpose+split
        const int t = blk - 2066;
        const int wsel = t >> 8;
        const int n0 = (t & 15) * 32, k0 = ((t >> 4) & 15) * 32;
        const int ncols = a.nc[wsel];
        if (n0 >= ncols) return;
        const float* W = a.src[wsel];
        {
            const int r = tid >> 3, c = (tid & 7) * 4;
            const float4 v = *(const float4*)(W + (size_t)(k0 + r) * ncols + n0 + c);
            tile[r][c + 0] = v.x; tile[r][c + 1] = v.y;
            tile[r][c + 2] = v.z; tile[r][c + 3] = v.w;
        }
        __syncthreads();
        {
            const int n = tid >> 3, k = (tid & 7) * 4;
            uint2 hp, lp;
            split_pack4(tile[k + 0][n], tile[k + 1][n], tile[k + 2][n], tile[k + 3][n], hp, lp);
            *(uint2*)(a.dh[wsel] + (size_t)(n0 + n) * 512 + k0 + k) = hp;
            *(uint2*)(a.dl[wsel] + (size_t)(n0 + n) * 512 + k0 + k) = lp;
        }
        return;
    }
    if (blk >= 2064) {            // bq_eff
        const int n = (blk - 2064) * 256 + tid;
        float v = bq[n];
        for (int k = 0; k < 512; ++k) v = fmaf(b_in[k], Wq[(size_t)k * 512 + n], v);
        bq_eff[n] = v;
        return;
    }
    if (blk >= 2060) {            // bkv concat
        const int i = (blk - 2060) * 256 + tid;
        bkv[i] = (i < 512) ? bk[i] : bv[i - 512];
        return;
    }
    if (blk >= 2048) {            // zero rowmeanv+logit (24576 floats)
        const int i = (blk - 2048) * 2048 + tid * 8;
        *(float4*)(zbuf + i) = make_float4(0.f, 0.f, 0.f, 0.f);
        *(float4*)(zbuf + i + 4) = make_float4(0.f, 0.f, 0.f, 0.f);
        return;
    }
    const int stride = 2048 * 256;
    for (int i = blk * 256 + tid; i < n8; i += stride) {
        const float4 va = *(const float4*)(x + (size_t)i * 8);
        const float4 vb = *(const float4*)(x + (size_t)i * 8 + 4);
        *(float4*)(cpy + (size_t)i * 8) = va;
        *(float4*)(cpy + (size_t)i * 8 + 4) = vb;
        uint2 h0, l0, h1, l1;
        split_pack4(va.x, va.y, va.z, va.w, h0, l0);
        split_pack4(vb.x, vb.y, vb.z, vb.w, h1, l1);
        *(uint2*)(hi + (size_t)i * 8) = h0;
        *(uint2*)(hi + (size_t)i * 8 + 4) = h1;
        *(uint2*)(lo + (size_t)i * 8) = l0;
        *(uint2*)(lo + (size_t)i * 8 + 4) = l1;
    }
}

// ---------------------------------------------------------------------------
// split-bf16 MFMA GEMM body, f32 A split in-kernel (info + winq)
// ---------------------------------------------------------------------------
#define GEMM_F32A_BODY(K_)                                                          \
    f32x4 acc[4][4];                                                                \
    _Pragma("unroll")                                                               \
    for (int i = 0; i < 4; ++i)                                                     \
        _Pragma("unroll")                                                           \
        for (int j = 0; j < 4; ++j)                                                 \
            _Pragma("unroll")                                                       \
            for (int r = 0; r < 4; ++r) acc[i][j][r] = 0.f;                         \
    const int ar = tid >> 4;                                                        \
    const int ak = (tid & 15) * 4;                                                  \
    int bsrow[4], bsf[4], bsoff[4];                                                 \
    _Pragma("unroll")                                                               \
    for (int it = 0; it < 4; ++it) {                                                \
        const int s = tid + 256 * it;                                               \
        bsrow[it] = s >> 3;                                                         \
        bsf[it] = s & 7;                                                            \
        bsoff[it] = bsrow[it] * 64 + ((bsf[it] ^ (bsrow[it] & 7)) << 3);            \
    }                                                                               \
    for (int k0 = 0; k0 < (K_); k0 += 64) {                                         \
        __syncthreads();                                                            \
        _Pragma("unroll")                                                           \
        for (int p = 0; p < 8; ++p) {                                               \
            const int r = p * 16 + ar;                                              \
            const float4 av = *(const float4*)(A + (size_t)(m0 + r) * (K_) + k0 + ak); \
            const int aoff = r * 128 + (((ak >> 3) ^ (r & 7)) << 4) + ((tid & 1) << 3); \
            uint2 hp, lp;                                                           \
            split_pack4(av.x, av.y, av.z, av.w, hp, lp);                            \
            *(uint2*)((char*)sAh + aoff) = hp;                                      \
            *(uint2*)((char*)sAl + aoff) = lp;                                      \
        }                                                                           \
        _Pragma("unroll")                                                           \
        for (int it = 0; it < 4; ++it) {                                            \
            const size_t bo = (size_t)(n0 + bsrow[it]) * (K_) + k0 + bsf[it] * 8;   \
            *(uint4*)(sBh + bsoff[it]) = *(const uint4*)(Bh + bo);                  \
            *(uint4*)(sBl + bsoff[it]) = *(const uint4*)(Bl + bo);                  \
        }                                                                           \
        __syncthreads();                                                            \
        _Pragma("unroll")                                                           \
        for (int ks = 0; ks < 2; ++ks) {                                            \
            short8 afh[4], afl[4], bfh[4], bfl[4];                                  \
            _Pragma("unroll")                                                       \
            for (int i = 0; i < 4; ++i) {                                           \
                const int row = wm * 64 + i * 16 + fr;                              \
                const int off = row * 128 + (((ks * 4 + fq4) ^ (row & 7)) << 4);    \
                afh[i] = *(const short8*)((const char*)sAh + off);                  \
                afl[i] = *(const short8*)((const char*)sAl + off);                  \
            }                                                                       \
            _Pragma("unroll")                                                       \
            for (int j = 0; j < 4; ++j) {                                           \
                const int row = wn * 64 + j * 16 + fr;                              \
                const int off = row * 128 + (((ks * 4 + fq4) ^ (row & 7)) << 4);    \
                bfh[j] = *(const short8*)((const char*)sBh + off);                  \
                bfl[j] = *(const short8*)((const char*)sBl + off);                  \
            }                                                                       \
            _Pragma("unroll")                                                       \
            for (int i = 0; i < 4; ++i)                                             \
                _Pragma("unroll")                                                   \
                for (int j = 0; j < 4; ++j) {                                       \
                    acc[i][j] = __builtin_amdgcn_mfma_f32_16x16x32_bf16(afh[i], bfh[j], acc[i][j], 0, 0, 0); \
                    acc[i][j] = __builtin_amdgcn_mfma_f32_16x16x32_bf16(afh[i], bfl[j], acc[i][j], 0, 0, 0); \
                    acc[i][j] = __builtin_amdgcn_mfma_f32_16x16x32_bf16(afl[i], bfh[j], acc[i][j], 0, 0, 0); \
                }                                                                   \
        }                                                                           \
    }

// ---------------------------------------------------------------------------
// MERGED info-GEMM + winq-GEMM (272 blocks)
// ---------------------------------------------------------------------------
__global__ __launch_bounds__(256) void gemm_info_winq(
    const float* __restrict__ new_info,
    const us* __restrict__ wtin_h, const us* __restrict__ wtin_l,
    const float* __restrict__ b_in,
    us* __restrict__ Oh, us* __restrict__ Ol,
    const float* __restrict__ W_in,
    const us* __restrict__ wtq_h, const us* __restrict__ wtq_l,
    us* __restrict__ wtinq_h, us* __restrict__ wtinq_l)
{
    __shared__ us sm[32768];
    us* sAh = sm;            us* sAl = sm + 8192;
    us* sBh = sm + 16384;    us* sBl = sm + 24576;
    const int tid = threadIdx.x, lane = tid & 63;
    const int wid = tid >> 6, wm = wid >> 1, wn = wid & 1;
    const int fr = lane & 15, fq4 = lane >> 4;
    const int id = blockIdx.x;
    const bool isInfo = (id < 256);
    int m0, n0;
    const float* A;
    const us *Bh, *Bl;
    if (isInfo) {
        m0 = (id >> 2) * 128; n0 = (id & 3) * 128;
        A = new_info; Bh = wtin_h; Bl = wtin_l;
    } else {
        const int t = id - 256;
        m0 = (t >> 2) * 128; n0 = (t & 3) * 128;
        A = W_in; Bh = wtq_h; Bl = wtq_l;
    }
    GEMM_F32A_BODY(512)

    if (isInfo) {
#pragma unroll
        for (int j = 0; j < 4; ++j) {
            const int col = n0 + wn * 64 + j * 16 + fr;
            const float bj = b_in[col];
#pragma unroll
            for (int i = 0; i < 4; ++i)
#pragma unroll
                for (int r = 0; r < 4; ++r) {
                    const int row = m0 + wm * 64 + i * 16 + fq4 * 4 + r;
                    const float v = acc[i][j][r] + bj;
                    const us hv = bf_hi(v);
                    Oh[(size_t)row * 512 + col] = hv;
                    Ol[(size_t)row * 512 + col] = bf_hi(v - bf_f(hv));
                }
        }
    } else {
#pragma unroll
        for (int j = 0; j < 4; ++j) {
            const int col = n0 + wn * 64 + j * 16 + fr;
#pragma unroll
            for (int i = 0; i < 4; ++i)
#pragma unroll
                for (int r = 0; r < 4; ++r) {
                    const int row = m0 + wm * 64 + i * 16 + fq4 * 4 + r;  // k
                    const float v = acc[i][j][r];
                    const us hv = bf_hi(v);
                    wtinq_h[(size_t)col * 512 + row] = hv;
                    wtinq_l[(size_t)col * 512 + row] = bf_hi(v - bf_f(hv));
                }
        }
    }
}

// ---------------------------------------------------------------------------
// PRE-SPLIT MFMA GEMM core (R9-validated DMA staging)
// ---------------------------------------------------------------------------
#define GEMM_PS_CORE(AhP, AlP, BhP, BlP, rsA_, K_)                                  \
    us* sAh = sm;            us* sAl = sm + 8192;                                   \
    us* sBh = sm + 16384;    us* sBl = sm + 24576;                                  \
    f32x4 acc[4][4];                                                                \
    _Pragma("unroll")                                                               \
    for (int i = 0; i < 4; ++i)                                                     \
        _Pragma("unroll")                                                           \
        for (int j = 0; j < 4; ++j)                                                 \
            _Pragma("unroll")                                                       \
            for (int r = 0; r < 4; ++r) acc[i][j][r] = 0.f;                         \
    const int fp = lane & 7, rsub = lane >> 3;                                      \
    const us* gsrc = (wid == 0) ? (AhP) : (wid == 1) ? (AlP)                        \
                   : (wid == 2) ? (BhP) : (BlP);                                    \
    const int grow0 = (wid < 2) ? m0 : n0;                                          \
    const int grs = (wid < 2) ? (rsA_) : (K_);                                      \
    us* lbase = sm + wid * 8192;                                                    \
    for (int k0 = 0; k0 < (K_); k0 += 64) {                                         \
        __syncthreads();                                                            \
        _Pragma("unroll")                                                           \
        for (int i = 0; i < 16; ++i) {                                              \
            const int row = i * 8 + rsub;                                           \
            const us* g = gsrc + (size_t)(grow0 + row) * grs + k0 +                 \
                          ((fp ^ (row & 7)) << 3);                                  \
            gload_lds16(g, lbase + i * 512);                                        \
        }                                                                           \
        __syncthreads();                                                            \
        _Pragma("unroll")                                                           \
        for (int ks = 0; ks < 2; ++ks) {                                            \
            short8 afh[4], afl[4], bfh[4], bfl[4];                                  \
            _Pragma("unroll")                                                       \
            for (int i = 0; i < 4; ++i) {                                           \
                const int row = wm * 64 + i * 16 + fr;                              \
                const int off = row * 128 + (((ks * 4 + fq4) ^ (row & 7)) << 4);    \
                afh[i] = *(const short8*)((const char*)sAh + off);                  \
                afl[i] = *(const short8*)((const char*)sAl + off);                  \
            }                                                                       \
            _Pragma("unroll")                                                       \
            for (int j = 0; j < 4; ++j) {                                           \
                const int row = wn * 64 + j * 16 + fr;                              \
                const int off = row * 128 + (((ks * 4 + fq4) ^ (row & 7)) << 4);    \
                bfh[j] = *(const short8*)((const char*)sBh + off);                  \
                bfl[j] = *(const short8*)((const char*)sBl + off);                  \
            }                                                                       \
            _Pragma("unroll")                                                       \
            for (int i = 0; i < 4; ++i)                                             \
                _Pragma("unroll")                                                   \
                for (int j = 0; j < 4; ++j) {                                       \
                    acc[i][j] = __builtin_amdgcn_mfma_f32_16x16x32_bf16(afh[i], bfh[j], acc[i][j], 0, 0, 0); \
                    acc[i][j] = __builtin_amdgcn_mfma_f32_16x16x32_bf16(afh[i], bfl[j], acc[i][j], 0, 0, 0); \
                    acc[i][j] = __builtin_amdgcn_mfma_f32_16x16x32_bf16(afl[i], bfh[j], acc[i][j], 0, 0, 0); \
                }                                                                   \
        }                                                                           \
    }

// ---------------------------------------------------------------------------
// h1-GEMM with FUSED Wi2 dot: computes relu(info@Wi1+bi1) tile and reduces
// partial logits (dot with Wi2 over this block's 128 cols) -> atomicAdd.
// h1 itself is never materialized. grid (2,64).
// ---------------------------------------------------------------------------
__global__ __launch_bounds__(256) void gemm_h1_logit(
    const us* __restrict__ Ah, const us* __restrict__ Al,
    const us* __restrict__ Bh, const us* __restrict__ Bl,
    const float* __restrict__ bias, const float* __restrict__ Wi2,
    float* __restrict__ logit)
{
    __shared__ us sm[32768];
    const int tid = threadIdx.x, lane = tid & 63;
    const int wid = tid >> 6, wm = wid >> 1, wn = wid & 1;
    const int fr = lane & 15, fq4 = lane >> 4;
    const int m0 = blockIdx.y * 128, n0 = blockIdx.x * 128;
    GEMM_PS_CORE(Ah, Al, Bh, Bl, 512, 512)

    float wsum[4][4];
#pragma unroll
    for (int i = 0; i < 4; ++i)
#pragma unroll
        for (int r = 0; r < 4; ++r) wsum[i][r] = 0.f;

#pragma unroll
    for (int j = 0; j < 4; ++j) {
        const int col = n0 + wn * 64 + j * 16 + fr;
        const float bj = bias[col];
        const float w2 = Wi2[col];
#pragma unroll
        for (int i = 0; i < 4; ++i)
#pragma unroll
            for (int r = 0; r < 4; ++r) {
                const float v = fmaxf(acc[i][j][r] + bj, 0.f);
                wsum[i][r] = fmaf(v, w2, wsum[i][r]);
            }
    }

    __syncthreads();                       // staging LDS reads done -> reuse
    float* red = (float*)sm;               // 128 row-partials
    if (tid < 128) red[tid] = 0.f;
    __syncthreads();
#pragma unroll
    for (int i = 0; i < 4; ++i)
#pragma unroll
        for (int r = 0; r < 4; ++r)
            atomicAdd(&red[wm * 64 + i * 16 + fq4 * 4 + r], wsum[i][r]);
    __syncthreads();
    if (tid < 128) atomicAdd(&logit[m0 + tid], red[tid]);
}

// ---------------------------------------------------------------------------
// importance finalize: 8 blocks; sigmoid(logit+bi2) -> imp, mean/last/exists
// ---------------------------------------------------------------------------
__global__ __launch_bounds__(256) void impfin(
    const float* __restrict__ logit, const float* __restrict__ bi2,
    float* __restrict__ imp, float* __restrict__ imp_mean,
    int* __restrict__ s_star, int* __restrict__ exists)
{
    const int b = blockIdx.x, tid = threadIdx.x;
    const float b0 = bi2[0];
    float sum = 0.f; int last = -1;
    for (int s = tid; s < SS; s += 256) {
        const float ip = 1.0f / (1.0f + expf(-(logit[b * SS + s] + b0)));
        imp[b * SS + s] = ip;
        sum += ip;
        if (ip > 0.5f) last = s;
    }
#pragma unroll
    for (int m = 1; m < 64; m <<= 1) {
        sum += __shfl_xor(sum, m);
        last = max(last, __shfl_xor(last, m));
    }
    __shared__ float ssum[4]; __shared__ int slast[4];
    if ((tid & 63) == 0) { ssum[tid >> 6] = sum; slast[tid >> 6] = last; }
    __syncthreads();
    if (tid == 0) {
        const float t = ssum[0] + ssum[1] + ssum[2] + ssum[3];
        const int ml = max(max(slast[0], slast[1]), max(slast[2], slast[3]));
        imp_mean[b] = t / (float)SS;
        exists[b] = (ml >= 0) ? 1 : 0;
        s_star[b] = (ml >= 0) ? ml : (SS - 1);
    }
}

// ---------------------------------------------------------------------------
// merged Q-GEMM + KV-GEMM: 1024 blocks. Q output PRE-SPLIT (qsph/qspl);
// K output pre-scaled by 1/8.
// ---------------------------------------------------------------------------
__global__ __launch_bounds__(256) void gemm_qkv_ps(
    const us* __restrict__ mbh, const us* __restrict__ mbl,
    const us* __restrict__ wtinq_h, const us* __restrict__ wtinq_l,
    const float* __restrict__ bq_eff,
    us* __restrict__ qsph, us* __restrict__ qspl,
    const us* __restrict__ iph, const us* __restrict__ ipl,
    const us* __restrict__ wtkv_h, const us* __restrict__ wtkv_l,
    const float* __restrict__ bkv,
    us* __restrict__ Kh, us* __restrict__ Kl,
    us* __restrict__ Vth, us* __restrict__ Vtl)
{
    __shared__ us sm[32768];
    const int tid = threadIdx.x, lane = tid & 63;
    const int wid = tid >> 6, wm = wid >> 1, wn = wid & 1;
    const int fr = lane & 15, fq4 = lane >> 4;
    const int id = blockIdx.x;
    const bool isQ = (id < 512);
    int m0, n0;
    const us *Ah, *Al, *Bh, *Bl;
    if (isQ) {
        m0 = (id >> 2) * 128; n0 = (id & 3) * 128;
        Ah = mbh; Al = mbl; Bh = wtinq_h; Bl = wtinq_l;
    } else {
        const int t = id - 512;
        m0 = (t >> 3) * 128; n0 = (t & 7) * 128;
        Ah = iph; Al = ipl; Bh = wtkv_h; Bl = wtkv_l;
    }
    GEMM_PS_CORE(Ah, Al, Bh, Bl, 512, 512)

    if (isQ) {
#pragma unroll
        for (int j = 0; j < 4; ++j) {
            const int col = n0 + wn * 64 + j * 16 + fr;
            const float bj = bq_eff[col];
#pragma unroll
            for (int i = 0; i < 4; ++i)
#pragma unroll
                for (int r = 0; r < 4; ++r) {
                    const int row = m0 + wm * 64 + i * 16 + fq4 * 4 + r;
                    const float v = acc[i][j][r] + bj;
                    const us hv = bf_hi(v);
                    qsph[(size_t)row * 512 + col] = hv;
                    qspl[(size_t)row * 512 + col] = bf_hi(v - bf_f(hv));
                }
        }
    } else if (n0 < 512) {
#pragma unroll
        for (int j = 0; j < 4; ++j) {
            const int col = n0 + wn * 64 + j * 16 + fr;
            const float bj = bkv[col];
#pragma unroll
            for (int i = 0; i < 4; ++i)
#pragma unroll
                for (int r = 0; r < 4; ++r) {
                    const int row = m0 + wm * 64 + i * 16 + fq4 * 4 + r;
                    const float v = (acc[i][j][r] + bj) * 0.125f;  // 1/sqrt(64)
                    const us hv = bf_hi(v);
                    Kh[(size_t)row * 512 + col] = hv;
                    Kl[(size_t)row * 512 + col] = bf_hi(v - bf_f(hv));
                }
        }
    } else {
#pragma unroll
        for (int j = 0; j < 4; ++j) {
            const int col = n0 + wn * 64 + j * 16 + fr;
            const float bj = bkv[col];
            const int d = col - 512;
#pragma unroll
            for (int i = 0; i < 4; ++i) {
                const int row0 = m0 + wm * 64 + i * 16 + fq4 * 4;
                uint2 hp, lp;
                split_pack4(acc[i][j][0] + bj, acc[i][j][1] + bj,
                            acc[i][j][2] + bj, acc[i][j][3] + bj, hp, lp);
                const size_t vo = ((size_t)(row0 >> 10) * 512 + d) * 1024 + (row0 & 1023);
                *(uint2*)(Vth + vo) = hp;
                *(uint2*)(Vtl + vo) = lp;
            }
        }
    }
}

// Wo-GEMM with fused rowmean
__global__ __launch_bounds__(256) void gemm_wo_ps(
    const us* __restrict__ Ah, const us* __restrict__ Al,
    const us* __restrict__ Bh, const us* __restrict__ Bl,
    const float* __restrict__ bias, float* __restrict__ C,
    const float* __restrict__ rowscale, float* __restrict__ rowmeanv)
{
    __shared__ us sm[32768];
    const int tid = threadIdx.x, lane = tid & 63;
    const int wid = tid >> 6, wm = wid >> 1, wn = wid & 1;
    const int fr = lane & 15, fq4 = lane >> 4;
    const int m0 = blockIdx.y * 128, n0 = blockIdx.x * 128;
    GEMM_PS_CORE(Ah, Al, Bh, Bl, 512, 512)

    float rsum[4][4];
#pragma unroll
    for (int i = 0; i < 4; ++i)
#pragma unroll
        for (int r = 0; r < 4; ++r) rsum[i][r] = 0.f;

#pragma unroll
    for (int j = 0; j < 4; ++j) {
        const int col = n0 + wn * 64 + j * 16 + fr;
        const float bj = bias[col];
#pragma unroll
        for (int i = 0; i < 4; ++i)
#pragma unroll
            for (int r = 0; r < 4; ++r) {
                const int row = m0 + wm * 64 + i * 16 + fq4 * 4 + r;
                const float v = (acc[i][j][r] + bj) * rowscale[row / MM];
                C[(size_t)row * 512 + col] = v;
                rsum[i][r] += v;
            }
    }

    __syncthreads();
    float* red = (float*)sm;
    if (tid < 128) red[tid] = 0.f;
    __syncthreads();
#pragma unroll
    for (int i = 0; i < 4; ++i)
#pragma unroll
        for (int r = 0; r < 4; ++r)
            atomicAdd(&red[wm * 64 + i * 16 + fq4 * 4 + r], rsum[i][r]);
    __syncthreads();
    if (tid < 128) atomicAdd(&rowmeanv[m0 + tid], red[tid] * (1.0f / 512.0f));
}

// ---------------------------------------------------------------------------
// MFMA flash attention: DMA-staged K/V, pre-split Q, defer-max skip.
// Epilogue emits pre-split hi/lo into mbh/mbl (dead after Q-GEMM).
// ---------------------------------------------------------------------------
__global__ __launch_bounds__(256) void attn_mfma(
    const us* __restrict__ Qh, const us* __restrict__ Ql,
    const us* __restrict__ Kh, const us* __restrict__ Kl,
    const us* __restrict__ Vth, const us* __restrict__ Vtl,
    us* __restrict__ aoh, us* __restrict__ aol)
{
    __shared__ us sm[24576];
    __shared__ float sSc[64];
    us* sKh = sm;            us* sKl = sm + 4096;
    us* sVh = sm + 8192;     us* sVl = sm + 12288;
    us* sPh = sm + 16384;    us* sPl = sm + 20480;

    const int tid = threadIdx.x, lane = tid & 63, w = tid >> 6;
    const int fr = lane & 15, fq4 = lane >> 4;

    const int wg = blockIdx.x;
    const int xcd = wg & 7, ix = wg >> 3;
    const int mt = ix & 31;
    const int pair = xcd + 8 * (ix >> 5);
    const int h = pair & 7, b = pair >> 3;
    const int m0 = mt * 64;

    const us* Qgh = Qh + ((size_t)(b * MM + m0)) * 512 + h * DHEAD;
    const us* Qgl = Ql + ((size_t)(b * MM + m0)) * 512 + h * DHEAD;
    const us* Kgh = Kh + ((size_t)b * SS) * 512 + h * DHEAD;
    const us* Kgl = Kl + ((size_t)b * SS) * 512 + h * DHEAD;
    const us* Vgh = Vth + ((size_t)b * 512 + h * DHEAD) * 1024;
    const us* Vgl = Vtl + ((size_t)b * 512 + h * DHEAD) * 1024;
    us* Oh = aoh + ((size_t)(b * MM + m0)) * 512 + h * DHEAD;
    us* Ol = aol + ((size_t)(b * MM + m0)) * 512 + h * DHEAD;

    short8 qfh[2], qfl[2];
#pragma unroll
    for (int ks = 0; ks < 2; ++ks) {
        const size_t qo = (size_t)(w * 16 + fr) * 512 + ks * 32 + fq4 * 8;
        qfh[ks] = *(const short8*)(Qgh + qo);
        qfl[ks] = *(const short8*)(Qgl + qo);
    }

    const int fp = lane & 7;
    const int rsub = lane >> 3;
    const bool isK = (w < 2);
    const us* gA = (w == 0) ? Kgh : (w == 1) ? Kgl : (w == 2) ? Vgh : Vgl;
    us* lbase = sm + w * 4096;

    f32x4 oacc[4];
#pragma unroll
    for (int j = 0; j < 4; ++j)
#pragma unroll
        for (int r = 0; r < 4; ++r) oacc[j][r] = 0.f;
    float mrun = -1e30f, lrun = 0.f;

    for (int t = 0; t < SS / 64; ++t) {
        __syncthreads();
        if (isK) {
#pragma unroll
            for (int i = 0; i < 8; ++i) {
                const int row = i * 8 + rsub;
                const us* g = gA + (size_t)(t * 64 + row) * 512 + ((fp ^ (row & 7)) << 3);
                gload_lds16(g, lbase + i * 512);
            }
        } else {
#pragma unroll
            for (int i = 0; i < 8; ++i) {
                const int row = i * 8 + rsub;
                const us* g = gA + (size_t)row * 1024 + t * 64 + ((fp ^ (row & 7)) << 3);
                gload_lds16(g, lbase + i * 512);
            }
        }
        __syncthreads();

        f32x4 stt[4];
#pragma unroll
        for (int fs = 0; fs < 4; ++fs)
#pragma unroll
            for (int r = 0; r < 4; ++r) stt[fs][r] = 0.f;
#pragma unroll
        for (int ks = 0; ks < 2; ++ks) {
            short8 kfh[4], kfl[4];
#pragma unroll
            for (int fs = 0; fs < 4; ++fs) {
                const int row = fs * 16 + fr;
                const int off = row * 128 + (((ks * 4 + fq4) ^ (row & 7)) << 4);
                kfh[fs] = *(const short8*)((const char*)sKh + off);
                kfl[fs] = *(const short8*)((const char*)sKl + off);
            }
#pragma unroll
            for (int fs = 0; fs < 4; ++fs) {
                stt[fs] = __builtin_amdgcn_mfma_f32_16x16x32_bf16(kfh[fs], qfh[ks], stt[fs], 0, 0, 0);
                stt[fs] = __builtin_amdgcn_mfma_f32_16x16x32_bf16(kfh[fs], qfl[ks], stt[fs], 0, 0, 0);
                stt[fs] = __builtin_amdgcn_mfma_f32_16x16x32_bf16(kfl[fs], qfh[ks], stt[fs], 0, 0, 0);
            }
        }

        float mx = stt[0][0];
#pragma unroll
        for (int fs = 0; fs < 4; ++fs)
#pragma unroll
            for (int r = 0; r < 4; ++r) mx = fmaxf(mx, stt[fs][r]);
        mx = fmaxf(mx, __shfl_xor(mx, 16));
        mx = fmaxf(mx, __shfl_xor(mx, 32));
        const bool grow = __any(mx > mrun);
        float scf = 1.f;
        if (grow) {
            const float nm = fmaxf(mrun, mx);
            scf = __expf(mrun - nm);
            mrun = nm;
            if (fq4 == 0) sSc[w * 16 + fr] = scf;
        }
        float ps = 0.f;
#pragma unroll
        for (int fs = 0; fs < 4; ++fs)
#pragma unroll
            for (int r = 0; r < 4; ++r) {
                const float p = __expf(stt[fs][r] - mrun);
                stt[fs][r] = p;
                ps += p;
            }
        ps += __shfl_xor(ps, 16);
        ps += __shfl_xor(ps, 32);
        lrun = lrun * scf + ps;

#pragma unroll
        for (int fs = 0; fs < 4; ++fs) {
            const int q = w * 16 + fr;
            const int flog = (fs << 1) | (fq4 >> 1);
            const int off = q * 128 + ((flog ^ (q & 7)) << 4) + ((fq4 & 1) << 3);
            uint2 hp, lp;
            split_pack4(stt[fs][0], stt[fs][1], stt[fs][2], stt[fs][3], hp, lp);
            *(uint2*)((char*)sPh + off) = hp;
            *(uint2*)((char*)sPl + off) = lp;
        }

        if (grow) {
#pragma unroll
            for (int r = 0; r < 4; ++r) {
                const float scv = sSc[w * 16 + fq4 * 4 + r];
#pragma unroll
                for (int fd = 0; fd < 4; ++fd) oacc[fd][r] *= scv;
            }
        }

#pragma unroll
        for (int ks = 0; ks < 2; ++ks) {
            short8 pfh, pfl, vfh[4], vfl[4];
            {
                const int row = w * 16 + fr;
                const int off = row * 128 + (((ks * 4 + fq4) ^ (row & 7)) << 4);
                pfh = *(const short8*)((const char*)sPh + off);
                pfl = *(const short8*)((const char*)sPl + off);
            }
#pragma unroll
            for (int fd = 0; fd < 4; ++fd) {
                const int row = fd * 16 + fr;
                const int off = row * 128 + (((ks * 4 + fq4) ^ (row & 7)) << 4);
                vfh[fd] = *(const short8*)((const char*)sVh + off);
                vfl[fd] = *(const short8*)((const char*)sVl + off);
            }
#pragma unroll
            for (int fd = 0; fd < 4; ++fd) {
                oacc[fd] = __builtin_amdgcn_mfma_f32_16x16x32_bf16(pfh, vfh[fd], oacc[fd], 0, 0, 0);
                oacc[fd] = __builtin_amdgcn_mfma_f32_16x16x32_bf16(pfh, vfl[fd], oacc[fd], 0, 0, 0);
                oacc[fd] = __builtin_amdgcn_mfma_f32_16x16x32_bf16(pfl, vfh[fd], oacc[fd], 0, 0, 0);
            }
        }
    }

    if (fq4 == 0) sSc[w * 16 + fr] = lrun;
#pragma unroll
    for (int r = 0; r < 4; ++r) {
        const float inv = 1.0f / sSc[w * 16 + fq4 * 4 + r];
        const int q = w * 16 + fq4 * 4 + r;
#pragma unroll
        for (int fd = 0; fd < 4; ++fd) {
            const float v = oacc[fd][r] * inv;
            const us hv = bf_hi(v);
            Oh[(size_t)q * 512 + fd * 16 + fr] = hv;
            Ol[(size_t)q * 512 + fd * 16 + fr] = bf_hi(v - bf_f(hv));
        }
    }
}

// ---------------------------------------------------------------------------
// MERGED argmax + update: 8 blocks; argmax -> LDS pos -> update MLP
// ---------------------------------------------------------------------------
__global__ __launch_bounds__(256) void argmax_update(
    const float* __restrict__ rm,
    const float* __restrict__ mb, const float* __restrict__ ni,
    const float* __restrict__ Wu1, const float* __restrict__ bu1,
    const float* __restrict__ Wu2, const float* __restrict__ bu2,
    const float* __restrict__ wwp, const int* __restrict__ s_star,
    const int* __restrict__ exists, float* __restrict__ outu)
{
    const int b = blockIdx.x, tid = threadIdx.x;
    __shared__ float comb[2 * DD];
    __shared__ float hu[HH];
    __shared__ float sv[4]; __shared__ int si[4];
    __shared__ int spos;

    {
        float best = -3.0e38f; int bidx = 1 << 30;
        for (int m = tid; m < MM; m += 256) {
            const float v = rm[b * MM + m];
            if (v > best || (v == best && m < bidx)) { best = v; bidx = m; }
        }
#pragma unroll
        for (int msk = 1; msk < 64; msk <<= 1) {
            const float ov = __shfl_xor(best, msk);
            const int oi = __shfl_xor(bidx, msk);
            if (ov > best || (ov == best && oi < bidx)) { best = ov; bidx = oi; }
        }
        if ((tid & 63) == 0) { sv[tid >> 6] = best; si[tid >> 6] = bidx; }
        __syncthreads();
        if (tid == 0) {
            for (int w = 1; w < 4; ++w)
                if (sv[w] > best || (sv[w] == best && si[w] < bidx)) { best = sv[w]; bidx = si[w]; }
            spos = bidx;
        }
        __syncthreads();
    }

    const int p = spos, ss = s_star[b], ex = exists[b];
    const float* oldp = mb + ((size_t)(b * MM + p)) * DD;
    const float* selp = ni + ((size_t)(b * SS + ss)) * DD;
    for (int i = tid; i < DD; i += 256) { comb[i] = oldp[i]; comb[DD + i] = selp[i]; }
    __syncthreads();
#pragma unroll
    for (int t = 0; t < 2; ++t) {
        const int n = tid + t * 256;
        float a = bu1[n];
        for (int k = 0; k < 2 * DD; ++k) a = fmaf(comb[k], Wu1[(size_t)k * HH + n], a);
        hu[n] = fmaxf(a, 0.f);
    }
    __syncthreads();
#pragma unroll
    for (int t = 0; t < 2; ++t) {
        const int n = tid + t * 256;
        float a = bu2[n];
        for (int k = 0; k < HH; ++k) a = fmaf(hu[k], Wu2[(size_t)k * HH + n], a);
        const float upd = tanhf(a);
        const float wwv = wwp[((size_t)(b * MM + p)) * HH + n];
        const float ov = oldp[n];
        outu[((size_t)(b * MM + p)) * DD + n] = ex ? fmaf(upd, wwv, ov) : ov;
    }
}

extern "C" void kernel_launch(void* const* d_in, const int* in_sizes, int n_in,
                              void* d_out, int out_size, void* d_ws, size_t ws_size,
                              hipStream_t stream)
{
    const float* new_info    = (const float*)d_in[0];
    const float* memory_bank = (const float*)d_in[1];
    const float* W_in = (const float*)d_in[2];  const float* b_in = (const float*)d_in[3];
    const float* Wq   = (const float*)d_in[4];  const float* bq   = (const float*)d_in[5];
    const float* Wk   = (const float*)d_in[6];  const float* bk   = (const float*)d_in[7];
    const float* Wv   = (const float*)d_in[8];  const float* bv   = (const float*)d_in[9];
    const float* Wo   = (const float*)d_in[10]; const float* bo   = (const float*)d_in[11];
    const float* Wi1  = (const float*)d_in[12]; const float* bi1  = (const float*)d_in[13];
    const float* Wi2  = (const float*)d_in[14]; const float* bi2  = (const float*)d_in[15];
    const float* Wu1  = (const float*)d_in[16]; const float* bu1  = (const float*)d_in[17];
    const float* Wu2  = (const float*)d_in[18]; const float* bu2  = (const float*)d_in[19];

    float* out = (float*)d_out;
    float* out_updated = out;                               // B*M*D
    float* out_ww      = out + (size_t)BB * MM * HH;        // B*M*H
    float* out_imp     = out + 2 * (size_t)BB * MM * HH;    // B*S

    // workspace layout (f32 units), ~125 MB
    float* ws = (float*)d_ws;
    float* qsp_rg    = ws;                                  // 8,388,608 (qsph/qspl)
    float* ip_sp     = qsp_rg + 8388608;                    // 4,194,304 (iph/ipl)
    float* mb_sp     = ip_sp + 4194304;                     // 8,388,608 (mbh/mbl; attn out reuses)
    float* kvreg     = mb_sp + 8388608;                     // 8,388,608 (K/V splits)
    float* wtf       = kvreg + 8388608;                     // 1,703,936 (us pairs)
    float* bq_eff    = wtf + 1703936;                       // 512
    float* bkv       = bq_eff + 512;                        // 1024
    float* rowmeanv  = bkv + 1024;                          // 16,384 (zeroed w/ logit)
    float* logit     = rowmeanv + 16384;                    // 8,192
    float* imp_mean  = logit + 8192;                        // 8
    int*   istar     = (int*)(imp_mean + BB);
    int*   iexists   = istar + BB;

    us* qsph = (us*)qsp_rg;        // [16384][512]
    us* qspl = qsph + 8388608;
    us* iph = (us*)ip_sp;          // [8192][512]
    us* ipl = iph + 4194304;
    us* mbh = (us*)mb_sp;          // [16384][512]
    us* mbl = mbh + 8388608;
    us* Kh  = (us*)kvreg;          // [8192][512]
    us* Kl  = Kh + 4194304;
    us* Vth = Kl + 4194304;        // [8][512][1024]
    us* Vtl = Vth + 4194304;

    us* wtin_h  = (us*)wtf;            us* wtin_l  = wtin_h + 262144;
    us* wtq_h   = wtin_l + 262144;     us* wtq_l   = wtq_h + 262144;
    us* wtkv_h  = wtq_l + 262144;      us* wtkv_l  = wtkv_h + 524288;   // [1024][512]
    us* wto_h   = wtkv_l + 524288;     us* wto_l   = wto_h + 262144;
    us* wtinq_h = wto_l + 262144;      us* wtinq_l = wtinq_h + 262144;
    us* wti1_h  = wtinq_l + 262144;    us* wti1_l  = wti1_h + 131072;   // [256][512]

    const dim3 blk(256);

    // 1) merged prep: mb copy+split, zero rowmeanv+logit, bkv, bq_eff, 6x transpose
    TSB ts;
    ts.src[0] = W_in; ts.dh[0] = wtin_h;          ts.dl[0] = wtin_l;          ts.nc[0] = 512;
    ts.src[1] = Wq;   ts.dh[1] = wtq_h;           ts.dl[1] = wtq_l;           ts.nc[1] = 512;
    ts.src[2] = Wk;   ts.dh[2] = wtkv_h;          ts.dl[2] = wtkv_l;          ts.nc[2] = 512;
    ts.src[3] = Wv;   ts.dh[3] = wtkv_h + 262144; ts.dl[3] = wtkv_l + 262144; ts.nc[3] = 512;
    ts.src[4] = Wo;   ts.dh[4] = wto_h;           ts.dl[4] = wto_l;           ts.nc[4] = 512;
    ts.src[5] = Wi1;  ts.dh[5] = wti1_h;          ts.dl[5] = wti1_l;          ts.nc[5] = 256;
    prep_all<<<dim3(2066 + 1536), blk, 0, stream>>>(memory_bank, out_updated,
                                                    mbh, mbl, 1048576, rowmeanv,
                                                    bk, bv, bkv, b_in, Wq, bq,
                                                    bq_eff, ts);

    // 2) merged info-GEMM (pre-split out) + winq-GEMM (transposed-split out)
    gemm_info_winq<<<dim3(272), blk, 0, stream>>>(new_info, wtin_h, wtin_l, b_in,
                                                  iph, ipl, W_in, wtq_h, wtq_l,
                                                  wtinq_h, wtinq_l);

    // 3) h1-GEMM with fused Wi2 dot -> logits (h1 never materialized)
    gemm_h1_logit<<<dim3(2, 64), blk, 0, stream>>>(iph, ipl, wti1_h, wti1_l,
                                                   bi1, Wi2, logit);

    // 4) importance finalize (sigmoid + stats), 8 blocks / 4 elems per thread
    impfin<<<dim3(BB), blk, 0, stream>>>(logit, bi2, out_imp,
                                         imp_mean, istar, iexists);

    // 5) merged Q-GEMM (pre-split out) + KV-GEMM (K pre-scaled 1/8)
    gemm_qkv_ps<<<dim3(1024), blk, 0, stream>>>(mbh, mbl, wtinq_h, wtinq_l,
                                                bq_eff, qsph, qspl,
                                                iph, ipl, wtkv_h, wtkv_l, bkv,
                                                Kh, Kl, Vth, Vtl);

    // 6) MFMA flash attention -> pre-split output into mbh/mbl (dead now)
    attn_mfma<<<dim3(2048), blk, 0, stream>>>(qsph, qspl, Kh, Kl, Vth, Vtl,
                                              mbh, mbl);

    // 7) output projection + imp_mean rowscale + fused rowmean
    gemm_wo_ps<<<dim3(4, 128), blk, 0, stream>>>(mbh, mbl, wto_h, wto_l,
                                                 bo, out_ww, imp_mean, rowmeanv);

    // 8) merged argmax + final row update
    argmax_update<<<dim3(BB), blk, 0, stream>>>(rowmeanv, memory_bank, new_info,
                                                Wu1, bu1, Wu2, bu2, out_ww,
                                                istar, iexists, out_updated);
}

// Round 15
// 424.111 us; speedup vs baseline: 1.3701x; 1.0532x over previous
//
#include <hip/hip_runtime.h>
#include <hip/hip_bf16.h>
#include <math.h>

// Problem constants (AttentionWriter): B=8,S=1024,M=2048,D=512,H=512,NH=8,Dh=64
#define BB 8
#define SS 1024
#define MM 2048
#define DD 512
#define HH 512
#define NHEAD 8
#define DHEAD 64

typedef __attribute__((ext_vector_type(8))) short short8;
typedef __attribute__((ext_vector_type(4))) float f32x4;
typedef unsigned short us;

// bf16 split helpers — native cvt (v_cvt_pk_bf16_f32), RNE
__device__ __forceinline__ us bf_hi(float x) {
    __hip_bfloat16 h = __float2bfloat16(x);
    return *reinterpret_cast<const us*>(&h);
}
__device__ __forceinline__ float bf_f(us h) {
    return __uint_as_float(((unsigned)h) << 16);
}
__device__ __forceinline__ void split_pack4(float a, float b, float c, float d,
                                            uint2& hp, uint2& lp) {
    us h0 = bf_hi(a), h1 = bf_hi(b), h2 = bf_hi(c), h3 = bf_hi(d);
    hp.x = (unsigned)h0 | ((unsigned)h1 << 16);
    hp.y = (unsigned)h2 | ((unsigned)h3 << 16);
    us l0 = bf_hi(a - bf_f(h0)), l1 = bf_hi(b - bf_f(h1));
    us l2 = bf_hi(c - bf_f(h2)), l3 = bf_hi(d - bf_f(h3));
    lp.x = (unsigned)l0 | ((unsigned)l1 << 16);
    lp.y = (unsigned)l2 | ((unsigned)l3 << 16);
}
// hi-only pack (for P: lo term dropped, P in [0,1] -> err <= 2^-9 rel)
__device__ __forceinline__ uint2 pack4_hi(float a, float b, float c, float d) {
    uint2 hp;
    hp.x = (unsigned)bf_hi(a) | ((unsigned)bf_hi(b) << 16);
    hp.y = (unsigned)bf_hi(c) | ((unsigned)bf_hi(d) << 16);
    return hp;
}

// async global->LDS DMA, 16B per lane; LDS dest = wave-uniform base + lane*16
__device__ __forceinline__ void gload_lds16(const void* g, void* l) {
    __builtin_amdgcn_global_load_lds(
        (__attribute__((address_space(1))) void*)(g),
        (__attribute__((address_space(3))) void*)(l), 16, 0, 0);
}

struct TSB {
    const float* src[6];
    us* dh[6];
    us* dl[6];
    int nc[6];
};

// ---------------------------------------------------------------------------
// MERGED prep: [0,2048) copy+split memory_bank; [2048,2060) zero
// rowmeanv+logit (24576 floats); [2060,2064) bkv; [2064,2066) bq_eff;
// [2066,2066+1536) 6x weight transpose+split
// ---------------------------------------------------------------------------
__global__ __launch_bounds__(256) void prep_all(
    const float* __restrict__ x, float* __restrict__ cpy,
    us* __restrict__ hi, us* __restrict__ lo, int n8, float* __restrict__ zbuf,
    const float* __restrict__ bk, const float* __restrict__ bv,
    float* __restrict__ bkv,
    const float* __restrict__ b_in, const float* __restrict__ Wq,
    const float* __restrict__ bq, float* __restrict__ bq_eff, TSB a)
{
    __shared__ float tile[32][33];
    const int blk = blockIdx.x, tid = threadIdx.x;
    if (blk >= 2066) {            // weight transpose+split
        const int t = blk - 2066;
        const int wsel = t >> 8;
        const int n0 = (t & 15) * 32, k0 = ((t >> 4) & 15) * 32;
        const int ncols = a.nc[wsel];
        if (n0 >= ncols) return;
        const float* W = a.src[wsel];
        {
            const int r = tid >> 3, c = (tid & 7) * 4;
            const float4 v = *(const float4*)(W + (size_t)(k0 + r) * ncols + n0 + c);
            tile[r][c + 0] = v.x; tile[r][c + 1] = v.y;
            tile[r][c + 2] = v.z; tile[r][c + 3] = v.w;
        }
        __syncthreads();
        {
            const int n = tid >> 3, k = (tid & 7) * 4;
            uint2 hp, lp;
            split_pack4(tile[k + 0][n], tile[k + 1][n], tile[k + 2][n], tile[k + 3][n], hp, lp);
            *(uint2*)(a.dh[wsel] + (size_t)(n0 + n) * 512 + k0 + k) = hp;
            *(uint2*)(a.dl[wsel] + (size_t)(n0 + n) * 512 + k0 + k) = lp;
        }
        return;
    }
    if (blk >= 2064) {            // bq_eff
        const int n = (blk - 2064) * 256 + tid;
        float v = bq[n];
        for (int k = 0; k < 512; ++k) v = fmaf(b_in[k], Wq[(size_t)k * 512 + n], v);
        bq_eff[n] = v;
        return;
    }
    if (blk >= 2060) {            // bkv concat
        const int i = (blk - 2060) * 256 + tid;
        bkv[i] = (i < 512) ? bk[i] : bv[i - 512];
        return;
    }
    if (blk >= 2048) {            // zero rowmeanv+logit (24576 floats)
        const int i = (blk - 2048) * 2048 + tid * 8;
        *(float4*)(zbuf + i) = make_float4(0.f, 0.f, 0.f, 0.f);
        *(float4*)(zbuf + i + 4) = make_float4(0.f, 0.f, 0.f, 0.f);
        return;
    }
    const int stride = 2048 * 256;
    for (int i = blk * 256 + tid; i < n8; i += stride) {
        const float4 va = *(const float4*)(x + (size_t)i * 8);
        const float4 vb = *(const float4*)(x + (size_t)i * 8 + 4);
        *(float4*)(cpy + (size_t)i * 8) = va;
        *(float4*)(cpy + (size_t)i * 8 + 4) = vb;
        uint2 h0, l0, h1, l1;
        split_pack4(va.x, va.y, va.z, va.w, h0, l0);
        split_pack4(vb.x, vb.y, vb.z, vb.w, h1, l1);
        *(uint2*)(hi + (size_t)i * 8) = h0;
        *(uint2*)(hi + (size_t)i * 8 + 4) = h1;
        *(uint2*)(lo + (size_t)i * 8) = l0;
        *(uint2*)(lo + (size_t)i * 8 + 4) = l1;
    }
}

// ---------------------------------------------------------------------------
// split-bf16 MFMA GEMM body, f32 A split in-kernel (info + winq)
// ---------------------------------------------------------------------------
#define GEMM_F32A_BODY(K_)                                                          \
    f32x4 acc[4][4];                                                                \
    _Pragma("unroll")                                                               \
    for (int i = 0; i < 4; ++i)                                                     \
        _Pragma("unroll")                                                           \
        for (int j = 0; j < 4; ++j)                                                 \
            _Pragma("unroll")                                                       \
            for (int r = 0; r < 4; ++r) acc[i][j][r] = 0.f;                         \
    const int ar = tid >> 4;                                                        \
    const int ak = (tid & 15) * 4;                                                  \
    int bsrow[4], bsf[4], bsoff[4];                                                 \
    _Pragma("unroll")                                                               \
    for (int it = 0; it < 4; ++it) {                                                \
        const int s = tid + 256 * it;                                               \
        bsrow[it] = s >> 3;                                                         \
        bsf[it] = s & 7;                                                            \
        bsoff[it] = bsrow[it] * 64 + ((bsf[it] ^ (bsrow[it] & 7)) << 3);            \
    }                                                                               \
    for (int k0 = 0; k0 < (K_); k0 += 64) {                                         \
        __syncthreads();                                                            \
        _Pragma("unroll")                                                           \
        for (int p = 0; p < 8; ++p) {                                               \
            const int r = p * 16 + ar;                                              \
            const float4 av = *(const float4*)(A + (size_t)(m0 + r) * (K_) + k0 + ak); \
            const int aoff = r * 128 + (((ak >> 3) ^ (r & 7)) << 4) + ((tid & 1) << 3); \
            uint2 hp, lp;                                                           \
            split_pack4(av.x, av.y, av.z, av.w, hp, lp);                            \
            *(uint2*)((char*)sAh + aoff) = hp;                                      \
            *(uint2*)((char*)sAl + aoff) = lp;                                      \
        }                                                                           \
        _Pragma("unroll")                                                           \
        for (int it = 0; it < 4; ++it) {                                            \
            const size_t bo = (size_t)(n0 + bsrow[it]) * (K_) + k0 + bsf[it] * 8;   \
            *(uint4*)(sBh + bsoff[it]) = *(const uint4*)(Bh + bo);                  \
            *(uint4*)(sBl + bsoff[it]) = *(const uint4*)(Bl + bo);                  \
        }                                                                           \
        __syncthreads();                                                            \
        _Pragma("unroll")                                                           \
        for (int ks = 0; ks < 2; ++ks) {                                            \
            short8 afh[4], afl[4], bfh[4], bfl[4];                                  \
            _Pragma("unroll")                                                       \
            for (int i = 0; i < 4; ++i) {                                           \
                const int row = wm * 64 + i * 16 + fr;                              \
                const int off = row * 128 + (((ks * 4 + fq4) ^ (row & 7)) << 4);    \
                afh[i] = *(const short8*)((const char*)sAh + off);                  \
                afl[i] = *(const short8*)((const char*)sAl + off);                  \
            }                                                                       \
            _Pragma("unroll")                                                       \
            for (int j = 0; j < 4; ++j) {                                           \
                const int row = wn * 64 + j * 16 + fr;                              \
                const int off = row * 128 + (((ks * 4 + fq4) ^ (row & 7)) << 4);    \
                bfh[j] = *(const short8*)((const char*)sBh + off);                  \
                bfl[j] = *(const short8*)((const char*)sBl + off);                  \
            }                                                                       \
            _Pragma("unroll")                                                       \
            for (int i = 0; i < 4; ++i)                                             \
                _Pragma("unroll")                                                   \
                for (int j = 0; j < 4; ++j) {                                       \
                    acc[i][j] = __builtin_amdgcn_mfma_f32_16x16x32_bf16(afh[i], bfh[j], acc[i][j], 0, 0, 0); \
                    acc[i][j] = __builtin_amdgcn_mfma_f32_16x16x32_bf16(afh[i], bfl[j], acc[i][j], 0, 0, 0); \
                    acc[i][j] = __builtin_amdgcn_mfma_f32_16x16x32_bf16(afl[i], bfh[j], acc[i][j], 0, 0, 0); \
                }                                                                   \
        }                                                                           \
    }

// ---------------------------------------------------------------------------
// MERGED info-GEMM + winq-GEMM (272 blocks)
// ---------------------------------------------------------------------------
__global__ __launch_bounds__(256) void gemm_info_winq(
    const float* __restrict__ new_info,
    const us* __restrict__ wtin_h, const us* __restrict__ wtin_l,
    const float* __restrict__ b_in,
    us* __restrict__ Oh, us* __restrict__ Ol,
    const float* __restrict__ W_in,
    const us* __restrict__ wtq_h, const us* __restrict__ wtq_l,
    us* __restrict__ wtinq_h, us* __restrict__ wtinq_l)
{
    __shared__ us sm[32768];
    us* sAh = sm;            us* sAl = sm + 8192;
    us* sBh = sm + 16384;    us* sBl = sm + 24576;
    const int tid = threadIdx.x, lane = tid & 63;
    const int wid = tid >> 6, wm = wid >> 1, wn = wid & 1;
    const int fr = lane & 15, fq4 = lane >> 4;
    const int id = blockIdx.x;
    const bool isInfo = (id < 256);
    int m0, n0;
    const float* A;
    const us *Bh, *Bl;
    if (isInfo) {
        m0 = (id >> 2) * 128; n0 = (id & 3) * 128;
        A = new_info; Bh = wtin_h; Bl = wtin_l;
    } else {
        const int t = id - 256;
        m0 = (t >> 2) * 128; n0 = (t & 3) * 128;
        A = W_in; Bh = wtq_h; Bl = wtq_l;
    }
    GEMM_F32A_BODY(512)

    if (isInfo) {
#pragma unroll
        for (int j = 0; j < 4; ++j) {
            const int col = n0 + wn * 64 + j * 16 + fr;
            const float bj = b_in[col];
#pragma unroll
            for (int i = 0; i < 4; ++i)
#pragma unroll
                for (int r = 0; r < 4; ++r) {
                    const int row = m0 + wm * 64 + i * 16 + fq4 * 4 + r;
                    const float v = acc[i][j][r] + bj;
                    const us hv = bf_hi(v);
                    Oh[(size_t)row * 512 + col] = hv;
                    Ol[(size_t)row * 512 + col] = bf_hi(v - bf_f(hv));
                }
        }
    } else {
#pragma unroll
        for (int j = 0; j < 4; ++j) {
            const int col = n0 + wn * 64 + j * 16 + fr;
#pragma unroll
            for (int i = 0; i < 4; ++i)
#pragma unroll
                for (int r = 0; r < 4; ++r) {
                    const int row = m0 + wm * 64 + i * 16 + fq4 * 4 + r;  // k
                    const float v = acc[i][j][r];
                    const us hv = bf_hi(v);
                    wtinq_h[(size_t)col * 512 + row] = hv;
                    wtinq_l[(size_t)col * 512 + row] = bf_hi(v - bf_f(hv));
                }
        }
    }
}

// ---------------------------------------------------------------------------
// PRE-SPLIT MFMA GEMM core (R9-validated DMA staging)
// ---------------------------------------------------------------------------
#define GEMM_PS_CORE(AhP, AlP, BhP, BlP, rsA_, K_)                                  \
    us* sAh = sm;            us* sAl = sm + 8192;                                   \
    us* sBh = sm + 16384;    us* sBl = sm + 24576;                                  \
    f32x4 acc[4][4];                                                                \
    _Pragma("unroll")                                                               \
    for (int i = 0; i < 4; ++i)                                                     \
        _Pragma("unroll")                                                           \
        for (int j = 0; j < 4; ++j)                                                 \
            _Pragma("unroll")                                                       \
            for (int r = 0; r < 4; ++r) acc[i][j][r] = 0.f;                         \
    const int fp = lane & 7, rsub = lane >> 3;                                      \
    const us* gsrc = (wid == 0) ? (AhP) : (wid == 1) ? (AlP)                        \
                   : (wid == 2) ? (BhP) : (BlP);                                    \
    const int grow0 = (wid < 2) ? m0 : n0;                                          \
    const int grs = (wid < 2) ? (rsA_) : (K_);                                      \
    us* lbase = sm + wid * 8192;                                                    \
    for (int k0 = 0; k0 < (K_); k0 += 64) {                                         \
        __syncthreads();                                                            \
        _Pragma("unroll")                                                           \
        for (int i = 0; i < 16; ++i) {                                              \
            const int row = i * 8 + rsub;                                           \
            const us* g = gsrc + (size_t)(grow0 + row) * grs + k0 +                 \
                          ((fp ^ (row & 7)) << 3);                                  \
            gload_lds16(g, lbase + i * 512);                                        \
        }                                                                           \
        __syncthreads();                                                            \
        _Pragma("unroll")                                                           \
        for (int ks = 0; ks < 2; ++ks) {                                            \
            short8 afh[4], afl[4], bfh[4], bfl[4];                                  \
            _Pragma("unroll")                                                       \
            for (int i = 0; i < 4; ++i) {                                           \
                const int row = wm * 64 + i * 16 + fr;                              \
                const int off = row * 128 + (((ks * 4 + fq4) ^ (row & 7)) << 4);    \
                afh[i] = *(const short8*)((const char*)sAh + off);                  \
                afl[i] = *(const short8*)((const char*)sAl + off);                  \
            }                                                                       \
            _Pragma("unroll")                                                       \
            for (int j = 0; j < 4; ++j) {                                           \
                const int row = wn * 64 + j * 16 + fr;                              \
                const int off = row * 128 + (((ks * 4 + fq4) ^ (row & 7)) << 4);    \
                bfh[j] = *(const short8*)((const char*)sBh + off);                  \
                bfl[j] = *(const short8*)((const char*)sBl + off);                  \
            }                                                                       \
            _Pragma("unroll")                                                       \
            for (int i = 0; i < 4; ++i)                                             \
                _Pragma("unroll")                                                   \
                for (int j = 0; j < 4; ++j) {                                       \
                    acc[i][j] = __builtin_amdgcn_mfma_f32_16x16x32_bf16(afh[i], bfh[j], acc[i][j], 0, 0, 0); \
                    acc[i][j] = __builtin_amdgcn_mfma_f32_16x16x32_bf16(afh[i], bfl[j], acc[i][j], 0, 0, 0); \
                    acc[i][j] = __builtin_amdgcn_mfma_f32_16x16x32_bf16(afl[i], bfh[j], acc[i][j], 0, 0, 0); \
                }                                                                   \
        }                                                                           \
    }

// ---------------------------------------------------------------------------
// h1-GEMM with FUSED Wi2 dot -> partial logits via atomicAdd; grid (2,64)
// ---------------------------------------------------------------------------
__global__ __launch_bounds__(256) void gemm_h1_logit(
    const us* __restrict__ Ah, const us* __restrict__ Al,
    const us* __restrict__ Bh, const us* __restrict__ Bl,
    const float* __restrict__ bias, const float* __restrict__ Wi2,
    float* __restrict__ logit)
{
    __shared__ us sm[32768];
    const int tid = threadIdx.x, lane = tid & 63;
    const int wid = tid >> 6, wm = wid >> 1, wn = wid & 1;
    const int fr = lane & 15, fq4 = lane >> 4;
    const int m0 = blockIdx.y * 128, n0 = blockIdx.x * 128;
    GEMM_PS_CORE(Ah, Al, Bh, Bl, 512, 512)

    float wsum[4][4];
#pragma unroll
    for (int i = 0; i < 4; ++i)
#pragma unroll
        for (int r = 0; r < 4; ++r) wsum[i][r] = 0.f;

#pragma unroll
    for (int j = 0; j < 4; ++j) {
        const int col = n0 + wn * 64 + j * 16 + fr;
        const float bj = bias[col];
        const float w2 = Wi2[col];
#pragma unroll
        for (int i = 0; i < 4; ++i)
#pragma unroll
            for (int r = 0; r < 4; ++r) {
                const float v = fmaxf(acc[i][j][r] + bj, 0.f);
                wsum[i][r] = fmaf(v, w2, wsum[i][r]);
            }
    }

    __syncthreads();
    float* red = (float*)sm;
    if (tid < 128) red[tid] = 0.f;
    __syncthreads();
#pragma unroll
    for (int i = 0; i < 4; ++i)
#pragma unroll
        for (int r = 0; r < 4; ++r)
            atomicAdd(&red[wm * 64 + i * 16 + fq4 * 4 + r], wsum[i][r]);
    __syncthreads();
    if (tid < 128) atomicAdd(&logit[m0 + tid], red[tid]);
}

// ---------------------------------------------------------------------------
// importance finalize: 8 blocks; sigmoid(logit+bi2) -> imp, mean/last/exists
// ---------------------------------------------------------------------------
__global__ __launch_bounds__(256) void impfin(
    const float* __restrict__ logit, const float* __restrict__ bi2,
    float* __restrict__ imp, float* __restrict__ imp_mean,
    int* __restrict__ s_star, int* __restrict__ exists)
{
    const int b = blockIdx.x, tid = threadIdx.x;
    const float b0 = bi2[0];
    float sum = 0.f; int last = -1;
    for (int s = tid; s < SS; s += 256) {
        const float ip = 1.0f / (1.0f + expf(-(logit[b * SS + s] + b0)));
        imp[b * SS + s] = ip;
        sum += ip;
        if (ip > 0.5f) last = s;
    }
#pragma unroll
    for (int m = 1; m < 64; m <<= 1) {
        sum += __shfl_xor(sum, m);
        last = max(last, __shfl_xor(last, m));
    }
    __shared__ float ssum[4]; __shared__ int slast[4];
    if ((tid & 63) == 0) { ssum[tid >> 6] = sum; slast[tid >> 6] = last; }
    __syncthreads();
    if (tid == 0) {
        const float t = ssum[0] + ssum[1] + ssum[2] + ssum[3];
        const int ml = max(max(slast[0], slast[1]), max(slast[2], slast[3]));
        imp_mean[b] = t / (float)SS;
        exists[b] = (ml >= 0) ? 1 : 0;
        s_star[b] = (ml >= 0) ? ml : (SS - 1);
    }
}

// ---------------------------------------------------------------------------
// merged Q-GEMM + KV-GEMM: 1024 blocks. Q output PRE-SPLIT (qsph/qspl);
// K output pre-scaled by 1/8.
// ---------------------------------------------------------------------------
__global__ __launch_bounds__(256) void gemm_qkv_ps(
    const us* __restrict__ mbh, const us* __restrict__ mbl,
    const us* __restrict__ wtinq_h, const us* __restrict__ wtinq_l,
    const float* __restrict__ bq_eff,
    us* __restrict__ qsph, us* __restrict__ qspl,
    const us* __restrict__ iph, const us* __restrict__ ipl,
    const us* __restrict__ wtkv_h, const us* __restrict__ wtkv_l,
    const float* __restrict__ bkv,
    us* __restrict__ Kh, us* __restrict__ Kl,
    us* __restrict__ Vth, us* __restrict__ Vtl)
{
    __shared__ us sm[32768];
    const int tid = threadIdx.x, lane = tid & 63;
    const int wid = tid >> 6, wm = wid >> 1, wn = wid & 1;
    const int fr = lane & 15, fq4 = lane >> 4;
    const int id = blockIdx.x;
    const bool isQ = (id < 512);
    int m0, n0;
    const us *Ah, *Al, *Bh, *Bl;
    if (isQ) {
        m0 = (id >> 2) * 128; n0 = (id & 3) * 128;
        Ah = mbh; Al = mbl; Bh = wtinq_h; Bl = wtinq_l;
    } else {
        const int t = id - 512;
        m0 = (t >> 3) * 128; n0 = (t & 7) * 128;
        Ah = iph; Al = ipl; Bh = wtkv_h; Bl = wtkv_l;
    }
    GEMM_PS_CORE(Ah, Al, Bh, Bl, 512, 512)

    if (isQ) {
#pragma unroll
        for (int j = 0; j < 4; ++j) {
            const int col = n0 + wn * 64 + j * 16 + fr;
            const float bj = bq_eff[col];
#pragma unroll
            for (int i = 0; i < 4; ++i)
#pragma unroll
                for (int r = 0; r < 4; ++r) {
                    const int row = m0 + wm * 64 + i * 16 + fq4 * 4 + r;
                    const float v = acc[i][j][r] + bj;
                    const us hv = bf_hi(v);
                    qsph[(size_t)row * 512 + col] = hv;
                    qspl[(size_t)row * 512 + col] = bf_hi(v - bf_f(hv));
                }
        }
    } else if (n0 < 512) {
#pragma unroll
        for (int j = 0; j < 4; ++j) {
            const int col = n0 + wn * 64 + j * 16 + fr;
            const float bj = bkv[col];
#pragma unroll
            for (int i = 0; i < 4; ++i)
#pragma unroll
                for (int r = 0; r < 4; ++r) {
                    const int row = m0 + wm * 64 + i * 16 + fq4 * 4 + r;
                    const float v = (acc[i][j][r] + bj) * 0.125f;  // 1/sqrt(64)
                    const us hv = bf_hi(v);
                    Kh[(size_t)row * 512 + col] = hv;
                    Kl[(size_t)row * 512 + col] = bf_hi(v - bf_f(hv));
                }
        }
    } else {
#pragma unroll
        for (int j = 0; j < 4; ++j) {
            const int col = n0 + wn * 64 + j * 16 + fr;
            const float bj = bkv[col];
            const int d = col - 512;
#pragma unroll
            for (int i = 0; i < 4; ++i) {
                const int row0 = m0 + wm * 64 + i * 16 + fq4 * 4;
                uint2 hp, lp;
                split_pack4(acc[i][j][0] + bj, acc[i][j][1] + bj,
                            acc[i][j][2] + bj, acc[i][j][3] + bj, hp, lp);
                const size_t vo = ((size_t)(row0 >> 10) * 512 + d) * 1024 + (row0 & 1023);
                *(uint2*)(Vth + vo) = hp;
                *(uint2*)(Vtl + vo) = lp;
            }
        }
    }
}

// Wo-GEMM with fused rowmean
__global__ __launch_bounds__(256) void gemm_wo_ps(
    const us* __restrict__ Ah, const us* __restrict__ Al,
    const us* __restrict__ Bh, const us* __restrict__ Bl,
    const float* __restrict__ bias, float* __restrict__ C,
    const float* __restrict__ rowscale, float* __restrict__ rowmeanv)
{
    __shared__ us sm[32768];
    const int tid = threadIdx.x, lane = tid & 63;
    const int wid = tid >> 6, wm = wid >> 1, wn = wid & 1;
    const int fr = lane & 15, fq4 = lane >> 4;
    const int m0 = blockIdx.y * 128, n0 = blockIdx.x * 128;
    GEMM_PS_CORE(Ah, Al, Bh, Bl, 512, 512)

    float rsum[4][4];
#pragma unroll
    for (int i = 0; i < 4; ++i)
#pragma unroll
        for (int r = 0; r < 4; ++r) rsum[i][r] = 0.f;

#pragma unroll
    for (int j = 0; j < 4; ++j) {
        const int col = n0 + wn * 64 + j * 16 + fr;
        const float bj = bias[col];
#pragma unroll
        for (int i = 0; i < 4; ++i)
#pragma unroll
            for (int r = 0; r < 4; ++r) {
                const int row = m0 + wm * 64 + i * 16 + fq4 * 4 + r;
                const float v = (acc[i][j][r] + bj) * rowscale[row / MM];
                C[(size_t)row * 512 + col] = v;
                rsum[i][r] += v;
            }
    }

    __syncthreads();
    float* red = (float*)sm;
    if (tid < 128) red[tid] = 0.f;
    __syncthreads();
#pragma unroll
    for (int i = 0; i < 4; ++i)
#pragma unroll
        for (int r = 0; r < 4; ++r)
            atomicAdd(&red[wm * 64 + i * 16 + fq4 * 4 + r], rsum[i][r]);
    __syncthreads();
    if (tid < 128) atomicAdd(&rowmeanv[m0 + tid], red[tid] * (1.0f / 512.0f));
}

// ---------------------------------------------------------------------------
// MFMA flash attention v5: DMA-staged K/V, pre-split Q, defer-max skip,
// P-lo term DROPPED (P in [0,1]; err <= 2^-9 rel => ~2e-4 in out_ww),
// sSc LDS replaced by __shfl (scale lives in-lane). LDS = 40960B exactly
// -> 4 blocks/CU (was 3). Epilogue emits pre-split hi/lo into mbh/mbl.
// ---------------------------------------------------------------------------
__global__ __launch_bounds__(256) void attn_mfma(
    const us* __restrict__ Qh, const us* __restrict__ Ql,
    const us* __restrict__ Kh, const us* __restrict__ Kl,
    const us* __restrict__ Vth, const us* __restrict__ Vtl,
    us* __restrict__ aoh, us* __restrict__ aol)
{
    __shared__ us sm[20480];     // sKh|sKl|sVh|sVl|sPh (4096 us each) = 40960B
    us* sKh = sm;            us* sKl = sm + 4096;
    us* sVh = sm + 8192;     us* sVl = sm + 12288;
    us* sPh = sm + 16384;

    const int tid = threadIdx.x, lane = tid & 63, w = tid >> 6;
    const int fr = lane & 15, fq4 = lane >> 4;

    const int wg = blockIdx.x;
    const int xcd = wg & 7, ix = wg >> 3;
    const int mt = ix & 31;
    const int pair = xcd + 8 * (ix >> 5);
    const int h = pair & 7, b = pair >> 3;
    const int m0 = mt * 64;

    const us* Qgh = Qh + ((size_t)(b * MM + m0)) * 512 + h * DHEAD;
    const us* Qgl = Ql + ((size_t)(b * MM + m0)) * 512 + h * DHEAD;
    const us* Kgh = Kh + ((size_t)b * SS) * 512 + h * DHEAD;
    const us* Kgl = Kl + ((size_t)b * SS) * 512 + h * DHEAD;
    const us* Vgh = Vth + ((size_t)b * 512 + h * DHEAD) * 1024;
    const us* Vgl = Vtl + ((size_t)b * 512 + h * DHEAD) * 1024;
    us* Oh = aoh + ((size_t)(b * MM + m0)) * 512 + h * DHEAD;
    us* Ol = aol + ((size_t)(b * MM + m0)) * 512 + h * DHEAD;

    short8 qfh[2], qfl[2];
#pragma unroll
    for (int ks = 0; ks < 2; ++ks) {
        const size_t qo = (size_t)(w * 16 + fr) * 512 + ks * 32 + fq4 * 8;
        qfh[ks] = *(const short8*)(Qgh + qo);
        qfl[ks] = *(const short8*)(Qgl + qo);
    }

    const int fp = lane & 7;
    const int rsub = lane >> 3;
    const bool isK = (w < 2);
    const us* gA = (w == 0) ? Kgh : (w == 1) ? Kgl : (w == 2) ? Vgh : Vgl;
    us* lbase = sm + w * 4096;

    f32x4 oacc[4];
#pragma unroll
    for (int j = 0; j < 4; ++j)
#pragma unroll
        for (int r = 0; r < 4; ++r) oacc[j][r] = 0.f;
    float mrun = -1e30f, lrun = 0.f;

    for (int t = 0; t < SS / 64; ++t) {
        __syncthreads();
        if (isK) {
#pragma unroll
            for (int i = 0; i < 8; ++i) {
                const int row = i * 8 + rsub;
                const us* g = gA + (size_t)(t * 64 + row) * 512 + ((fp ^ (row & 7)) << 3);
                gload_lds16(g, lbase + i * 512);
            }
        } else {
#pragma unroll
            for (int i = 0; i < 8; ++i) {
                const int row = i * 8 + rsub;
                const us* g = gA + (size_t)row * 1024 + t * 64 + ((fp ^ (row & 7)) << 3);
                gload_lds16(g, lbase + i * 512);
            }
        }
        __syncthreads();

        f32x4 stt[4];
#pragma unroll
        for (int fs = 0; fs < 4; ++fs)
#pragma unroll
            for (int r = 0; r < 4; ++r) stt[fs][r] = 0.f;
#pragma unroll
        for (int ks = 0; ks < 2; ++ks) {
            short8 kfh[4], kfl[4];
#pragma unroll
            for (int fs = 0; fs < 4; ++fs) {
                const int row = fs * 16 + fr;
                const int off = row * 128 + (((ks * 4 + fq4) ^ (row & 7)) << 4);
                kfh[fs] = *(const short8*)((const char*)sKh + off);
                kfl[fs] = *(const short8*)((const char*)sKl + off);
            }
#pragma unroll
            for (int fs = 0; fs < 4; ++fs) {
                stt[fs] = __builtin_amdgcn_mfma_f32_16x16x32_bf16(kfh[fs], qfh[ks], stt[fs], 0, 0, 0);
                stt[fs] = __builtin_amdgcn_mfma_f32_16x16x32_bf16(kfh[fs], qfl[ks], stt[fs], 0, 0, 0);
                stt[fs] = __builtin_amdgcn_mfma_f32_16x16x32_bf16(kfl[fs], qfh[ks], stt[fs], 0, 0, 0);
            }
        }

        // ---- online softmax; scales live in-lane, distributed via __shfl
        float mx = stt[0][0];
#pragma unroll
        for (int fs = 0; fs < 4; ++fs)
#pragma unroll
            for (int r = 0; r < 4; ++r) mx = fmaxf(mx, stt[fs][r]);
        mx = fmaxf(mx, __shfl_xor(mx, 16));
        mx = fmaxf(mx, __shfl_xor(mx, 32));
        const bool grow = __any(mx > mrun);
        float scf = 1.f;
        if (grow) {
            const float nm = fmaxf(mrun, mx);
            scf = __expf(mrun - nm);
            mrun = nm;
        }
        float ps = 0.f;
#pragma unroll
        for (int fs = 0; fs < 4; ++fs)
#pragma unroll
            for (int r = 0; r < 4; ++r) {
                const float p = __expf(stt[fs][r] - mrun);
                stt[fs][r] = p;
                ps += p;
            }
        ps += __shfl_xor(ps, 16);
        ps += __shfl_xor(ps, 32);
        lrun = lrun * scf + ps;

        // ---- write P[q][s] hi only (wave-private rows)
#pragma unroll
        for (int fs = 0; fs < 4; ++fs) {
            const int q = w * 16 + fr;
            const int flog = (fs << 1) | (fq4 >> 1);
            const int off = q * 128 + ((flog ^ (q & 7)) << 4) + ((fq4 & 1) << 3);
            *(uint2*)((char*)sPh + off) = pack4_hi(stt[fs][0], stt[fs][1],
                                                  stt[fs][2], stt[fs][3]);
        }

        // ---- rescale oacc via shfl (row q=fq4*4+r lives in lane fq4*4+r)
        if (grow) {
#pragma unroll
            for (int r = 0; r < 4; ++r) {
                const float scv = __shfl(scf, fq4 * 4 + r);
#pragma unroll
                for (int fd = 0; fd < 4; ++fd) oacc[fd][r] *= scv;
            }
        }

        // ---- PV: 2-term (Ph*Vh + Ph*Vl)
#pragma unroll
        for (int ks = 0; ks < 2; ++ks) {
            short8 pfh, vfh[4], vfl[4];
            {
                const int row = w * 16 + fr;
                const int off = row * 128 + (((ks * 4 + fq4) ^ (row & 7)) << 4);
                pfh = *(const short8*)((const char*)sPh + off);
            }
#pragma unroll
            for (int fd = 0; fd < 4; ++fd) {
                const int row = fd * 16 + fr;
                const int off = row * 128 + (((ks * 4 + fq4) ^ (row & 7)) << 4);
                vfh[fd] = *(const short8*)((const char*)sVh + off);
                vfl[fd] = *(const short8*)((const char*)sVl + off);
            }
#pragma unroll
            for (int fd = 0; fd < 4; ++fd) {
                oacc[fd] = __builtin_amdgcn_mfma_f32_16x16x32_bf16(pfh, vfh[fd], oacc[fd], 0, 0, 0);
                oacc[fd] = __builtin_amdgcn_mfma_f32_16x16x32_bf16(pfh, vfl[fd], oacc[fd], 0, 0, 0);
            }
        }
    }

    // ---- normalize + store pre-split (lrun distributed via shfl)
#pragma unroll
    for (int r = 0; r < 4; ++r) {
        const float inv = 1.0f / __shfl(lrun, fq4 * 4 + r);
        const int q = w * 16 + fq4 * 4 + r;
#pragma unroll
        for (int fd = 0; fd < 4; ++fd) {
            const float v = oacc[fd][r] * inv;
            const us hv = bf_hi(v);
            Oh[(size_t)q * 512 + fd * 16 + fr] = hv;
            Ol[(size_t)q * 512 + fd * 16 + fr] = bf_hi(v - bf_f(hv));
        }
    }
}

// ---------------------------------------------------------------------------
// MERGED argmax + update: 8 blocks; argmax -> LDS pos -> update MLP
// ---------------------------------------------------------------------------
__global__ __launch_bounds__(256) void argmax_update(
    const float* __restrict__ rm,
    const float* __restrict__ mb, const float* __restrict__ ni,
    const float* __restrict__ Wu1, const float* __restrict__ bu1,
    const float* __restrict__ Wu2, const float* __restrict__ bu2,
    const float* __restrict__ wwp, const int* __restrict__ s_star,
    const int* __restrict__ exists, float* __restrict__ outu)
{
    const int b = blockIdx.x, tid = threadIdx.x;
    __shared__ float comb[2 * DD];
    __shared__ float hu[HH];
    __shared__ float sv[4]; __shared__ int si[4];
    __shared__ int spos;

    {
        float best = -3.0e38f; int bidx = 1 << 30;
        for (int m = tid; m < MM; m += 256) {
            const float v = rm[b * MM + m];
            if (v > best || (v == best && m < bidx)) { best = v; bidx = m; }
        }
#pragma unroll
        for (int msk = 1; msk < 64; msk <<= 1) {
            const float ov = __shfl_xor(best, msk);
            const int oi = __shfl_xor(bidx, msk);
            if (ov > best || (ov == best && oi < bidx)) { best = ov; bidx = oi; }
        }
        if ((tid & 63) == 0) { sv[tid >> 6] = best; si[tid >> 6] = bidx; }
        __syncthreads();
        if (tid == 0) {
            for (int w = 1; w < 4; ++w)
                if (sv[w] > best || (sv[w] == best && si[w] < bidx)) { best = sv[w]; bidx = si[w]; }
            spos = bidx;
        }
        __syncthreads();
    }

    const int p = spos, ss = s_star[b], ex = exists[b];
    const float* oldp = mb + ((size_t)(b * MM + p)) * DD;
    const float* selp = ni + ((size_t)(b * SS + ss)) * DD;
    for (int i = tid; i < DD; i += 256) { comb[i] = oldp[i]; comb[DD + i] = selp[i]; }
    __syncthreads();
#pragma unroll
    for (int t = 0; t < 2; ++t) {
        const int n = tid + t * 256;
        float a = bu1[n];
        for (int k = 0; k < 2 * DD; ++k) a = fmaf(comb[k], Wu1[(size_t)k * HH + n], a);
        hu[n] = fmaxf(a, 0.f);
    }
    __syncthreads();
#pragma unroll
    for (int t = 0; t < 2; ++t) {
        const int n = tid + t * 256;
        float a = bu2[n];
        for (int k = 0; k < HH; ++k) a = fmaf(hu[k], Wu2[(size_t)k * HH + n], a);
        const float upd = tanhf(a);
        const float wwv = wwp[((size_t)(b * MM + p)) * HH + n];
        const float ov = oldp[n];
        outu[((size_t)(b * MM + p)) * DD + n] = ex ? fmaf(upd, wwv, ov) : ov;
    }
}

extern "C" void kernel_launch(void* const* d_in, const int* in_sizes, int n_in,
                              void* d_out, int out_size, void* d_ws, size_t ws_size,
                              hipStream_t stream)
{
    const float* new_info    = (const float*)d_in[0];
    const float* memory_bank = (const float*)d_in[1];
    const float* W_in = (const float*)d_in[2];  const float* b_in = (const float*)d_in[3];
    const float* Wq   = (const float*)d_in[4];  const float* bq   = (const float*)d_in[5];
    const float* Wk   = (const float*)d_in[6];  const float* bk   = (const float*)d_in[7];
    const float* Wv   = (const float*)d_in[8];  const float* bv   = (const float*)d_in[9];
    const float* Wo   = (const float*)d_in[10]; const float* bo   = (const float*)d_in[11];
    const float* Wi1  = (const float*)d_in[12]; const float* bi1  = (const float*)d_in[13];
    const float* Wi2  = (const float*)d_in[14]; const float* bi2  = (const float*)d_in[15];
    const float* Wu1  = (const float*)d_in[16]; const float* bu1  = (const float*)d_in[17];
    const float* Wu2  = (const float*)d_in[18]; const float* bu2  = (const float*)d_in[19];

    float* out = (float*)d_out;
    float* out_updated = out;                               // B*M*D
    float* out_ww      = out + (size_t)BB * MM * HH;        // B*M*H
    float* out_imp     = out + 2 * (size_t)BB * MM * HH;    // B*S

    // workspace layout (f32 units), ~125 MB
    float* ws = (float*)d_ws;
    float* qsp_rg    = ws;                                  // 8,388,608 (qsph/qspl)
    float* ip_sp     = qsp_rg + 8388608;                    // 4,194,304 (iph/ipl)
    float* mb_sp     = ip_sp + 4194304;                     // 8,388,608 (mbh/mbl; attn out reuses)
    float* kvreg     = mb_sp + 8388608;                     // 8,388,608 (K/V splits)
    float* wtf       = kvreg + 8388608;                     // 1,703,936 (us pairs)
    float* bq_eff    = wtf + 1703936;                       // 512
    float* bkv       = bq_eff + 512;                        // 1024
    float* rowmeanv  = bkv + 1024;                          // 16,384 (zeroed w/ logit)
    float* logit     = rowmeanv + 16384;                    // 8,192
    float* imp_mean  = logit + 8192;                        // 8
    int*   istar     = (int*)(imp_mean + BB);
    int*   iexists   = istar + BB;

    us* qsph = (us*)qsp_rg;        // [16384][512]
    us* qspl = qsph + 8388608;
    us* iph = (us*)ip_sp;          // [8192][512]
    us* ipl = iph + 4194304;
    us* mbh = (us*)mb_sp;          // [16384][512]
    us* mbl = mbh + 8388608;
    us* Kh  = (us*)kvreg;          // [8192][512]
    us* Kl  = Kh + 4194304;
    us* Vth = Kl + 4194304;        // [8][512][1024]
    us* Vtl = Vth + 4194304;

    us* wtin_h  = (us*)wtf;            us* wtin_l  = wtin_h + 262144;
    us* wtq_h   = wtin_l + 262144;     us* wtq_l   = wtq_h + 262144;
    us* wtkv_h  = wtq_l + 262144;      us* wtkv_l  = wtkv_h + 524288;   // [1024][512]
    us* wto_h   = wtkv_l + 524288;     us* wto_l   = wto_h + 262144;
    us* wtinq_h = wto_l + 262144;      us* wtinq_l = wtinq_h + 262144;
    us* wti1_h  = wtinq_l + 262144;    us* wti1_l  = wti1_h + 131072;   // [256][512]

    const dim3 blk(256);

    // 1) merged prep: mb copy+split, zero rowmeanv+logit, bkv, bq_eff, 6x transpose
    TSB ts;
    ts.src[0] = W_in; ts.dh[0] = wtin_h;          ts.dl[0] = wtin_l;          ts.nc[0] = 512;
    ts.src[1] = Wq;   ts.dh[1] = wtq_h;           ts.dl[1] = wtq_l;           ts.nc[1] = 512;
    ts.src[2] = Wk;   ts.dh[2] = wtkv_h;          ts.dl[2] = wtkv_l;          ts.nc[2] = 512;
    ts.src[3] = Wv;   ts.dh[3] = wtkv_h + 262144; ts.dl[3] = wtkv_l + 262144; ts.nc[3] = 512;
    ts.src[4] = Wo;   ts.dh[4] = wto_h;           ts.dl[4] = wto_l;           ts.nc[4] = 512;
    ts.src[5] = Wi1;  ts.dh[5] = wti1_h;          ts.dl[5] = wti1_l;          ts.nc[5] = 256;
    prep_all<<<dim3(2066 + 1536), blk, 0, stream>>>(memory_bank, out_updated,
                                                    mbh, mbl, 1048576, rowmeanv,
                                                    bk, bv, bkv, b_in, Wq, bq,
                                                    bq_eff, ts);

    // 2) merged info-GEMM (pre-split out) + winq-GEMM (transposed-split out)
    gemm_info_winq<<<dim3(272), blk, 0, stream>>>(new_info, wtin_h, wtin_l, b_in,
                                                  iph, ipl, W_in, wtq_h, wtq_l,
                                                  wtinq_h, wtinq_l);

    // 3) h1-GEMM with fused Wi2 dot -> logits (h1 never materialized)
    gemm_h1_logit<<<dim3(2, 64), blk, 0, stream>>>(iph, ipl, wti1_h, wti1_l,
                                                   bi1, Wi2, logit);

    // 4) importance finalize (sigmoid + stats)
    impfin<<<dim3(BB), blk, 0, stream>>>(logit, bi2, out_imp,
                                         imp_mean, istar, iexists);

    // 5) merged Q-GEMM (pre-split out) + KV-GEMM (K pre-scaled 1/8)
    gemm_qkv_ps<<<dim3(1024), blk, 0, stream>>>(mbh, mbl, wtinq_h, wtinq_l,
                                                bq_eff, qsph, qspl,
                                                iph, ipl, wtkv_h, wtkv_l, bkv,
                                                Kh, Kl, Vth, Vtl);

    // 6) MFMA flash attention -> pre-split output into mbh/mbl (dead now)
    attn_mfma<<<dim3(2048), blk, 0, stream>>>(qsph, qspl, Kh, Kl, Vth, Vtl,
                                              mbh, mbl);

    // 7) output projection + imp_mean rowscale + fused rowmean
    gemm_wo_ps<<<dim3(4, 128), blk, 0, stream>>>(mbh, mbl, wto_h, wto_l,
                                                 bo, out_ww, imp_mean, rowmeanv);

    // 8) merged argmax + final row update
    argmax_update<<<dim3(BB), blk, 0, stream>>>(rowmeanv, memory_bank, new_info,
                                                Wu1, bu1, Wu2, bu2, out_ww,
                                                istar, iexists, out_updated);
}

// Round 16
// 409.073 us; speedup vs baseline: 1.4205x; 1.0368x over previous
//
#include <hip/hip_runtime.h>
#include <hip/hip_bf16.h>
#include <math.h>

// Problem constants (AttentionWriter): B=8,S=1024,M=2048,D=512,H=512,NH=8,Dh=64
#define BB 8
#define SS 1024
#define MM 2048
#define DD 512
#define HH 512
#define NHEAD 8
#define DHEAD 64

typedef __attribute__((ext_vector_type(8))) short short8;
typedef __attribute__((ext_vector_type(4))) float f32x4;
typedef unsigned short us;

// bf16 split helpers — native cvt (v_cvt_pk_bf16_f32), RNE
__device__ __forceinline__ us bf_hi(float x) {
    __hip_bfloat16 h = __float2bfloat16(x);
    return *reinterpret_cast<const us*>(&h);
}
__device__ __forceinline__ float bf_f(us h) {
    return __uint_as_float(((unsigned)h) << 16);
}
__device__ __forceinline__ void split_pack4(float a, float b, float c, float d,
                                            uint2& hp, uint2& lp) {
    us h0 = bf_hi(a), h1 = bf_hi(b), h2 = bf_hi(c), h3 = bf_hi(d);
    hp.x = (unsigned)h0 | ((unsigned)h1 << 16);
    hp.y = (unsigned)h2 | ((unsigned)h3 << 16);
    us l0 = bf_hi(a - bf_f(h0)), l1 = bf_hi(b - bf_f(h1));
    us l2 = bf_hi(c - bf_f(h2)), l3 = bf_hi(d - bf_f(h3));
    lp.x = (unsigned)l0 | ((unsigned)l1 << 16);
    lp.y = (unsigned)l2 | ((unsigned)l3 << 16);
}
// hi-only pack (for P: lo term dropped, P in [0,1] -> err <= 2^-9 rel)
__device__ __forceinline__ uint2 pack4_hi(float a, float b, float c, float d) {
    uint2 hp;
    hp.x = (unsigned)bf_hi(a) | ((unsigned)bf_hi(b) << 16);
    hp.y = (unsigned)bf_hi(c) | ((unsigned)bf_hi(d) << 16);
    return hp;
}

// async global->LDS DMA, 16B per lane; LDS dest = wave-uniform base + lane*16
__device__ __forceinline__ void gload_lds16(const void* g, void* l) {
    __builtin_amdgcn_global_load_lds(
        (__attribute__((address_space(1))) void*)(g),
        (__attribute__((address_space(3))) void*)(l), 16, 0, 0);
}

struct TSB {
    const float* src[6];
    us* dh[6];
    us* dl[6];
    int nc[6];
};

// ---------------------------------------------------------------------------
// MERGED prep: [0,2048) copy+split memory_bank; [2048,2060) zero
// rowmeanv+logit (24576 floats); [2060,2064) bkv; [2064,2066) bq_eff;
// [2066,2066+1536) 6x weight transpose+split
// ---------------------------------------------------------------------------
__global__ __launch_bounds__(256) void prep_all(
    const float* __restrict__ x, float* __restrict__ cpy,
    us* __restrict__ hi, us* __restrict__ lo, int n8, float* __restrict__ zbuf,
    const float* __restrict__ bk, const float* __restrict__ bv,
    float* __restrict__ bkv,
    const float* __restrict__ b_in, const float* __restrict__ Wq,
    const float* __restrict__ bq, float* __restrict__ bq_eff, TSB a)
{
    __shared__ float tile[32][33];
    const int blk = blockIdx.x, tid = threadIdx.x;
    if (blk >= 2066) {            // weight transpose+split
        const int t = blk - 2066;
        const int wsel = t >> 8;
        const int n0 = (t & 15) * 32, k0 = ((t >> 4) & 15) * 32;
        const int ncols = a.nc[wsel];
        if (n0 >= ncols) return;
        const float* W = a.src[wsel];
        {
            const int r = tid >> 3, c = (tid & 7) * 4;
            const float4 v = *(const float4*)(W + (size_t)(k0 + r) * ncols + n0 + c);
            tile[r][c + 0] = v.x; tile[r][c + 1] = v.y;
            tile[r][c + 2] = v.z; tile[r][c + 3] = v.w;
        }
        __syncthreads();
        {
            const int n = tid >> 3, k = (tid & 7) * 4;
            uint2 hp, lp;
            split_pack4(tile[k + 0][n], tile[k + 1][n], tile[k + 2][n], tile[k + 3][n], hp, lp);
            *(uint2*)(a.dh[wsel] + (size_t)(n0 + n) * 512 + k0 + k) = hp;
            *(uint2*)(a.dl[wsel] + (size_t)(n0 + n) * 512 + k0 + k) = lp;
        }
        return;
    }
    if (blk >= 2064) {            // bq_eff
        const int n = (blk - 2064) * 256 + tid;
        float v = bq[n];
        for (int k = 0; k < 512; ++k) v = fmaf(b_in[k], Wq[(size_t)k * 512 + n], v);
        bq_eff[n] = v;
        return;
    }
    if (blk >= 2060) {            // bkv concat
        const int i = (blk - 2060) * 256 + tid;
        bkv[i] = (i < 512) ? bk[i] : bv[i - 512];
        return;
    }
    if (blk >= 2048) {            // zero rowmeanv+logit (24576 floats)
        const int i = (blk - 2048) * 2048 + tid * 8;
        *(float4*)(zbuf + i) = make_float4(0.f, 0.f, 0.f, 0.f);
        *(float4*)(zbuf + i + 4) = make_float4(0.f, 0.f, 0.f, 0.f);
        return;
    }
    const int stride = 2048 * 256;
    for (int i = blk * 256 + tid; i < n8; i += stride) {
        const float4 va = *(const float4*)(x + (size_t)i * 8);
        const float4 vb = *(const float4*)(x + (size_t)i * 8 + 4);
        *(float4*)(cpy + (size_t)i * 8) = va;
        *(float4*)(cpy + (size_t)i * 8 + 4) = vb;
        uint2 h0, l0, h1, l1;
        split_pack4(va.x, va.y, va.z, va.w, h0, l0);
        split_pack4(vb.x, vb.y, vb.z, vb.w, h1, l1);
        *(uint2*)(hi + (size_t)i * 8) = h0;
        *(uint2*)(hi + (size_t)i * 8 + 4) = h1;
        *(uint2*)(lo + (size_t)i * 8) = l0;
        *(uint2*)(lo + (size_t)i * 8 + 4) = l1;
    }
}

// ---------------------------------------------------------------------------
// split-bf16 MFMA GEMM body, f32 A split in-kernel (info + winq)
// ---------------------------------------------------------------------------
#define GEMM_F32A_BODY(K_)                                                          \
    f32x4 acc[4][4];                                                                \
    _Pragma("unroll")                                                               \
    for (int i = 0; i < 4; ++i)                                                     \
        _Pragma("unroll")                                                           \
        for (int j = 0; j < 4; ++j)                                                 \
            _Pragma("unroll")                                                       \
            for (int r = 0; r < 4; ++r) acc[i][j][r] = 0.f;                         \
    const int ar = tid >> 4;                                                        \
    const int ak = (tid & 15) * 4;                                                  \
    int bsrow[4], bsf[4], bsoff[4];                                                 \
    _Pragma("unroll")                                                               \
    for (int it = 0; it < 4; ++it) {                                                \
        const int s = tid + 256 * it;                                               \
        bsrow[it] = s >> 3;                                                         \
        bsf[it] = s & 7;                                                            \
        bsoff[it] = bsrow[it] * 64 + ((bsf[it] ^ (bsrow[it] & 7)) << 3);            \
    }                                                                               \
    for (int k0 = 0; k0 < (K_); k0 += 64) {                                         \
        __syncthreads();                                                            \
        _Pragma("unroll")                                                           \
        for (int p = 0; p < 8; ++p) {                                               \
            const int r = p * 16 + ar;                                              \
            const float4 av = *(const float4*)(A + (size_t)(m0 + r) * (K_) + k0 + ak); \
            const int aoff = r * 128 + (((ak >> 3) ^ (r & 7)) << 4) + ((tid & 1) << 3); \
            uint2 hp, lp;                                                           \
            split_pack4(av.x, av.y, av.z, av.w, hp, lp);                            \
            *(uint2*)((char*)sAh + aoff) = hp;                                      \
            *(uint2*)((char*)sAl + aoff) = lp;                                      \
        }                                                                           \
        _Pragma("unroll")                                                           \
        for (int it = 0; it < 4; ++it) {                                            \
            const size_t bo = (size_t)(n0 + bsrow[it]) * (K_) + k0 + bsf[it] * 8;   \
            *(uint4*)(sBh + bsoff[it]) = *(const uint4*)(Bh + bo);                  \
            *(uint4*)(sBl + bsoff[it]) = *(const uint4*)(Bl + bo);                  \
        }                                                                           \
        __syncthreads();                                                            \
        _Pragma("unroll")                                                           \
        for (int ks = 0; ks < 2; ++ks) {                                            \
            short8 afh[4], afl[4], bfh[4], bfl[4];                                  \
            _Pragma("unroll")                                                       \
            for (int i = 0; i < 4; ++i) {                                           \
                const int row = wm * 64 + i * 16 + fr;                              \
                const int off = row * 128 + (((ks * 4 + fq4) ^ (row & 7)) << 4);    \
                afh[i] = *(const short8*)((const char*)sAh + off);                  \
                afl[i] = *(const short8*)((const char*)sAl + off);                  \
            }                                                                       \
            _Pragma("unroll")                                                       \
            for (int j = 0; j < 4; ++j) {                                           \
                const int row = wn * 64 + j * 16 + fr;                              \
                const int off = row * 128 + (((ks * 4 + fq4) ^ (row & 7)) << 4);    \
                bfh[j] = *(const short8*)((const char*)sBh + off);                  \
                bfl[j] = *(const short8*)((const char*)sBl + off);                  \
            }                                                                       \
            _Pragma("unroll")                                                       \
            for (int i = 0; i < 4; ++i)                                             \
                _Pragma("unroll")                                                   \
                for (int j = 0; j < 4; ++j) {                                       \
                    acc[i][j] = __builtin_amdgcn_mfma_f32_16x16x32_bf16(afh[i], bfh[j], acc[i][j], 0, 0, 0); \
                    acc[i][j] = __builtin_amdgcn_mfma_f32_16x16x32_bf16(afh[i], bfl[j], acc[i][j], 0, 0, 0); \
                    acc[i][j] = __builtin_amdgcn_mfma_f32_16x16x32_bf16(afl[i], bfh[j], acc[i][j], 0, 0, 0); \
                }                                                                   \
        }                                                                           \
    }

// ---------------------------------------------------------------------------
// MERGED info-GEMM + winq-GEMM (272 blocks)
// ---------------------------------------------------------------------------
__global__ __launch_bounds__(256) void gemm_info_winq(
    const float* __restrict__ new_info,
    const us* __restrict__ wtin_h, const us* __restrict__ wtin_l,
    const float* __restrict__ b_in,
    us* __restrict__ Oh, us* __restrict__ Ol,
    const float* __restrict__ W_in,
    const us* __restrict__ wtq_h, const us* __restrict__ wtq_l,
    us* __restrict__ wtinq_h, us* __restrict__ wtinq_l)
{
    __shared__ us sm[32768];
    us* sAh = sm;            us* sAl = sm + 8192;
    us* sBh = sm + 16384;    us* sBl = sm + 24576;
    const int tid = threadIdx.x, lane = tid & 63;
    const int wid = tid >> 6, wm = wid >> 1, wn = wid & 1;
    const int fr = lane & 15, fq4 = lane >> 4;
    const int id = blockIdx.x;
    const bool isInfo = (id < 256);
    int m0, n0;
    const float* A;
    const us *Bh, *Bl;
    if (isInfo) {
        m0 = (id >> 2) * 128; n0 = (id & 3) * 128;
        A = new_info; Bh = wtin_h; Bl = wtin_l;
    } else {
        const int t = id - 256;
        m0 = (t >> 2) * 128; n0 = (t & 3) * 128;
        A = W_in; Bh = wtq_h; Bl = wtq_l;
    }
    GEMM_F32A_BODY(512)

    if (isInfo) {
#pragma unroll
        for (int j = 0; j < 4; ++j) {
            const int col = n0 + wn * 64 + j * 16 + fr;
            const float bj = b_in[col];
#pragma unroll
            for (int i = 0; i < 4; ++i)
#pragma unroll
                for (int r = 0; r < 4; ++r) {
                    const int row = m0 + wm * 64 + i * 16 + fq4 * 4 + r;
                    const float v = acc[i][j][r] + bj;
                    const us hv = bf_hi(v);
                    Oh[(size_t)row * 512 + col] = hv;
                    Ol[(size_t)row * 512 + col] = bf_hi(v - bf_f(hv));
                }
        }
    } else {
#pragma unroll
        for (int j = 0; j < 4; ++j) {
            const int col = n0 + wn * 64 + j * 16 + fr;
#pragma unroll
            for (int i = 0; i < 4; ++i)
#pragma unroll
                for (int r = 0; r < 4; ++r) {
                    const int row = m0 + wm * 64 + i * 16 + fq4 * 4 + r;  // k
                    const float v = acc[i][j][r];
                    const us hv = bf_hi(v);
                    wtinq_h[(size_t)col * 512 + row] = hv;
                    wtinq_l[(size_t)col * 512 + row] = bf_hi(v - bf_f(hv));
                }
        }
    }
}

// ---------------------------------------------------------------------------
// PRE-SPLIT MFMA GEMM core (R9-validated DMA staging)
// ---------------------------------------------------------------------------
#define GEMM_PS_CORE(AhP, AlP, BhP, BlP, rsA_, K_)                                  \
    us* sAh = sm;            us* sAl = sm + 8192;                                   \
    us* sBh = sm + 16384;    us* sBl = sm + 24576;                                  \
    f32x4 acc[4][4];                                                                \
    _Pragma("unroll")                                                               \
    for (int i = 0; i < 4; ++i)                                                     \
        _Pragma("unroll")                                                           \
        for (int j = 0; j < 4; ++j)                                                 \
            _Pragma("unroll")                                                       \
            for (int r = 0; r < 4; ++r) acc[i][j][r] = 0.f;                         \
    const int fp = lane & 7, rsub = lane >> 3;                                      \
    const us* gsrc = (wid == 0) ? (AhP) : (wid == 1) ? (AlP)                        \
                   : (wid == 2) ? (BhP) : (BlP);                                    \
    const int grow0 = (wid < 2) ? m0 : n0;                                          \
    const int grs = (wid < 2) ? (rsA_) : (K_);                                      \
    us* lbase = sm + wid * 8192;                                                    \
    for (int k0 = 0; k0 < (K_); k0 += 64) {                                         \
        __syncthreads();                                                            \
        _Pragma("unroll")                                                           \
        for (int i = 0; i < 16; ++i) {                                              \
            const int row = i * 8 + rsub;                                           \
            const us* g = gsrc + (size_t)(grow0 + row) * grs + k0 +                 \
                          ((fp ^ (row & 7)) << 3);                                  \
            gload_lds16(g, lbase + i * 512);                                        \
        }                                                                           \
        __syncthreads();                                                            \
        _Pragma("unroll")                                                           \
        for (int ks = 0; ks < 2; ++ks) {                                            \
            short8 afh[4], afl[4], bfh[4], bfl[4];                                  \
            _Pragma("unroll")                                                       \
            for (int i = 0; i < 4; ++i) {                                           \
                const int row = wm * 64 + i * 16 + fr;                              \
                const int off = row * 128 + (((ks * 4 + fq4) ^ (row & 7)) << 4);    \
                afh[i] = *(const short8*)((const char*)sAh + off);                  \
                afl[i] = *(const short8*)((const char*)sAl + off);                  \
            }                                                                       \
            _Pragma("unroll")                                                       \
            for (int j = 0; j < 4; ++j) {                                           \
                const int row = wn * 64 + j * 16 + fr;                              \
                const int off = row * 128 + (((ks * 4 + fq4) ^ (row & 7)) << 4);    \
                bfh[j] = *(const short8*)((const char*)sBh + off);                  \
                bfl[j] = *(const short8*)((const char*)sBl + off);                  \
            }                                                                       \
            _Pragma("unroll")                                                       \
            for (int i = 0; i < 4; ++i)                                             \
                _Pragma("unroll")                                                   \
                for (int j = 0; j < 4; ++j) {                                       \
                    acc[i][j] = __builtin_amdgcn_mfma_f32_16x16x32_bf16(afh[i], bfh[j], acc[i][j], 0, 0, 0); \
                    acc[i][j] = __builtin_amdgcn_mfma_f32_16x16x32_bf16(afh[i], bfl[j], acc[i][j], 0, 0, 0); \
                    acc[i][j] = __builtin_amdgcn_mfma_f32_16x16x32_bf16(afl[i], bfh[j], acc[i][j], 0, 0, 0); \
                }                                                                   \
        }                                                                           \
    }

// ---------------------------------------------------------------------------
// MERGED Q-GEMM + KV-GEMM + h1-logit GEMM: 1152 blocks.
//  id<512:        Q = mb@wtinq + bq_eff -> pre-split qsph/qspl
//  512<=id<1024:  KV = ip@wtkv + bkv -> K pre-split (scaled 1/8) / Vt pre-split
//  id>=1024:      h1 = relu(ip@wti1+bi1), fused Wi2 dot -> logit atomicAdd
// ---------------------------------------------------------------------------
__global__ __launch_bounds__(256) void gemm_qkvh1_ps(
    const us* __restrict__ mbh, const us* __restrict__ mbl,
    const us* __restrict__ wtinq_h, const us* __restrict__ wtinq_l,
    const float* __restrict__ bq_eff,
    us* __restrict__ qsph, us* __restrict__ qspl,
    const us* __restrict__ iph, const us* __restrict__ ipl,
    const us* __restrict__ wtkv_h, const us* __restrict__ wtkv_l,
    const float* __restrict__ bkv,
    us* __restrict__ Kh, us* __restrict__ Kl,
    us* __restrict__ Vth, us* __restrict__ Vtl,
    const us* __restrict__ wti1_h, const us* __restrict__ wti1_l,
    const float* __restrict__ bi1, const float* __restrict__ Wi2,
    float* __restrict__ logit)
{
    __shared__ us sm[32768];
    const int tid = threadIdx.x, lane = tid & 63;
    const int wid = tid >> 6, wm = wid >> 1, wn = wid & 1;
    const int fr = lane & 15, fq4 = lane >> 4;
    const int id = blockIdx.x;
    int m0, n0;
    const us *Ah, *Al, *Bh, *Bl;
    if (id < 512) {
        m0 = (id >> 2) * 128; n0 = (id & 3) * 128;
        Ah = mbh; Al = mbl; Bh = wtinq_h; Bl = wtinq_l;
    } else if (id < 1024) {
        const int t = id - 512;
        m0 = (t >> 3) * 128; n0 = (t & 7) * 128;
        Ah = iph; Al = ipl; Bh = wtkv_h; Bl = wtkv_l;
    } else {
        const int t = id - 1024;
        m0 = (t >> 1) * 128; n0 = (t & 1) * 128;
        Ah = iph; Al = ipl; Bh = wti1_h; Bl = wti1_l;
    }
    GEMM_PS_CORE(Ah, Al, Bh, Bl, 512, 512)

    if (id < 512) {
#pragma unroll
        for (int j = 0; j < 4; ++j) {
            const int col = n0 + wn * 64 + j * 16 + fr;
            const float bj = bq_eff[col];
#pragma unroll
            for (int i = 0; i < 4; ++i)
#pragma unroll
                for (int r = 0; r < 4; ++r) {
                    const int row = m0 + wm * 64 + i * 16 + fq4 * 4 + r;
                    const float v = acc[i][j][r] + bj;
                    const us hv = bf_hi(v);
                    qsph[(size_t)row * 512 + col] = hv;
                    qspl[(size_t)row * 512 + col] = bf_hi(v - bf_f(hv));
                }
        }
    } else if (id < 1024 && n0 < 512) {
#pragma unroll
        for (int j = 0; j < 4; ++j) {
            const int col = n0 + wn * 64 + j * 16 + fr;
            const float bj = bkv[col];
#pragma unroll
            for (int i = 0; i < 4; ++i)
#pragma unroll
                for (int r = 0; r < 4; ++r) {
                    const int row = m0 + wm * 64 + i * 16 + fq4 * 4 + r;
                    const float v = (acc[i][j][r] + bj) * 0.125f;  // 1/sqrt(64)
                    const us hv = bf_hi(v);
                    Kh[(size_t)row * 512 + col] = hv;
                    Kl[(size_t)row * 512 + col] = bf_hi(v - bf_f(hv));
                }
        }
    } else if (id < 1024) {
#pragma unroll
        for (int j = 0; j < 4; ++j) {
            const int col = n0 + wn * 64 + j * 16 + fr;
            const float bj = bkv[col];
            const int d = col - 512;
#pragma unroll
            for (int i = 0; i < 4; ++i) {
                const int row0 = m0 + wm * 64 + i * 16 + fq4 * 4;
                uint2 hp, lp;
                split_pack4(acc[i][j][0] + bj, acc[i][j][1] + bj,
                            acc[i][j][2] + bj, acc[i][j][3] + bj, hp, lp);
                const size_t vo = ((size_t)(row0 >> 10) * 512 + d) * 1024 + (row0 & 1023);
                *(uint2*)(Vth + vo) = hp;
                *(uint2*)(Vtl + vo) = lp;
            }
        }
    } else {
        // h1 + fused Wi2 dot -> logit partials
        float wsum[4][4];
#pragma unroll
        for (int i = 0; i < 4; ++i)
#pragma unroll
            for (int r = 0; r < 4; ++r) wsum[i][r] = 0.f;
#pragma unroll
        for (int j = 0; j < 4; ++j) {
            const int col = n0 + wn * 64 + j * 16 + fr;
            const float bj = bi1[col];
            const float w2 = Wi2[col];
#pragma unroll
            for (int i = 0; i < 4; ++i)
#pragma unroll
                for (int r = 0; r < 4; ++r) {
                    const float v = fmaxf(acc[i][j][r] + bj, 0.f);
                    wsum[i][r] = fmaf(v, w2, wsum[i][r]);
                }
        }
        __syncthreads();
        float* red = (float*)sm;
        if (tid < 128) red[tid] = 0.f;
        __syncthreads();
#pragma unroll
        for (int i = 0; i < 4; ++i)
#pragma unroll
            for (int r = 0; r < 4; ++r)
                atomicAdd(&red[wm * 64 + i * 16 + fq4 * 4 + r], wsum[i][r]);
        __syncthreads();
        if (tid < 128) atomicAdd(&logit[m0 + tid], red[tid]);
    }
}

// Wo-GEMM with fused rowmean
__global__ __launch_bounds__(256) void gemm_wo_ps(
    const us* __restrict__ Ah, const us* __restrict__ Al,
    const us* __restrict__ Bh, const us* __restrict__ Bl,
    const float* __restrict__ bias, float* __restrict__ C,
    const float* __restrict__ rowscale, float* __restrict__ rowmeanv)
{
    __shared__ us sm[32768];
    const int tid = threadIdx.x, lane = tid & 63;
    const int wid = tid >> 6, wm = wid >> 1, wn = wid & 1;
    const int fr = lane & 15, fq4 = lane >> 4;
    const int m0 = blockIdx.y * 128, n0 = blockIdx.x * 128;
    GEMM_PS_CORE(Ah, Al, Bh, Bl, 512, 512)

    float rsum[4][4];
#pragma unroll
    for (int i = 0; i < 4; ++i)
#pragma unroll
        for (int r = 0; r < 4; ++r) rsum[i][r] = 0.f;

#pragma unroll
    for (int j = 0; j < 4; ++j) {
        const int col = n0 + wn * 64 + j * 16 + fr;
        const float bj = bias[col];
#pragma unroll
        for (int i = 0; i < 4; ++i)
#pragma unroll
            for (int r = 0; r < 4; ++r) {
                const int row = m0 + wm * 64 + i * 16 + fq4 * 4 + r;
                const float v = (acc[i][j][r] + bj) * rowscale[row / MM];
                C[(size_t)row * 512 + col] = v;
                rsum[i][r] += v;
            }
    }

    __syncthreads();
    float* red = (float*)sm;
    if (tid < 128) red[tid] = 0.f;
    __syncthreads();
#pragma unroll
    for (int i = 0; i < 4; ++i)
#pragma unroll
        for (int r = 0; r < 4; ++r)
            atomicAdd(&red[wm * 64 + i * 16 + fq4 * 4 + r], rsum[i][r]);
    __syncthreads();
    if (tid < 128) atomicAdd(&rowmeanv[m0 + tid], red[tid] * (1.0f / 512.0f));
}

// ---------------------------------------------------------------------------
// MFMA flash attention v5.1 + fused impfin (blocks >= 2048).
// DMA-staged K/V, pre-split Q, defer-max skip, P-lo dropped, shfl scales,
// s_setprio around MFMA clusters. LDS 40960B -> 4 blocks/CU.
// ---------------------------------------------------------------------------
__global__ __launch_bounds__(256) void attn_mfma(
    const us* __restrict__ Qh, const us* __restrict__ Ql,
    const us* __restrict__ Kh, const us* __restrict__ Kl,
    const us* __restrict__ Vth, const us* __restrict__ Vtl,
    us* __restrict__ aoh, us* __restrict__ aol,
    const float* __restrict__ logit, const float* __restrict__ bi2,
    float* __restrict__ imp, float* __restrict__ imp_mean,
    int* __restrict__ s_star, int* __restrict__ exists)
{
    __shared__ us sm[20480];     // sKh|sKl|sVh|sVl|sPh (4096 us each) = 40960B
    const int tid = threadIdx.x, lane = tid & 63, w = tid >> 6;

    if (blockIdx.x >= 2048) {    // ---- fused importance finalize (8 blocks)
        const int b = blockIdx.x - 2048;
        const float b0 = bi2[0];
        float sum = 0.f; int last = -1;
        for (int s = tid; s < SS; s += 256) {
            const float ip = 1.0f / (1.0f + expf(-(logit[b * SS + s] + b0)));
            imp[b * SS + s] = ip;
            sum += ip;
            if (ip > 0.5f) last = s;
        }
#pragma unroll
        for (int m = 1; m < 64; m <<= 1) {
            sum += __shfl_xor(sum, m);
            last = max(last, __shfl_xor(last, m));
        }
        float* ssum = (float*)sm;
        int* slast = (int*)(sm + 16);
        if (lane == 0) { ssum[w] = sum; slast[w] = last; }
        __syncthreads();
        if (tid == 0) {
            const float t = ssum[0] + ssum[1] + ssum[2] + ssum[3];
            const int ml = max(max(slast[0], slast[1]), max(slast[2], slast[3]));
            imp_mean[b] = t / (float)SS;
            exists[b] = (ml >= 0) ? 1 : 0;
            s_star[b] = (ml >= 0) ? ml : (SS - 1);
        }
        return;
    }

    us* sKh = sm;            us* sKl = sm + 4096;
    us* sVh = sm + 8192;     us* sVl = sm + 12288;
    us* sPh = sm + 16384;

    const int fr = lane & 15, fq4 = lane >> 4;

    const int wg = blockIdx.x;
    const int xcd = wg & 7, ix = wg >> 3;
    const int mt = ix & 31;
    const int pair = xcd + 8 * (ix >> 5);
    const int h = pair & 7, b = pair >> 3;
    const int m0 = mt * 64;

    const us* Qgh = Qh + ((size_t)(b * MM + m0)) * 512 + h * DHEAD;
    const us* Qgl = Ql + ((size_t)(b * MM + m0)) * 512 + h * DHEAD;
    const us* Kgh = Kh + ((size_t)b * SS) * 512 + h * DHEAD;
    const us* Kgl = Kl + ((size_t)b * SS) * 512 + h * DHEAD;
    const us* Vgh = Vth + ((size_t)b * 512 + h * DHEAD) * 1024;
    const us* Vgl = Vtl + ((size_t)b * 512 + h * DHEAD) * 1024;
    us* Oh = aoh + ((size_t)(b * MM + m0)) * 512 + h * DHEAD;
    us* Ol = aol + ((size_t)(b * MM + m0)) * 512 + h * DHEAD;

    short8 qfh[2], qfl[2];
#pragma unroll
    for (int ks = 0; ks < 2; ++ks) {
        const size_t qo = (size_t)(w * 16 + fr) * 512 + ks * 32 + fq4 * 8;
        qfh[ks] = *(const short8*)(Qgh + qo);
        qfl[ks] = *(const short8*)(Qgl + qo);
    }

    const int fp = lane & 7;
    const int rsub = lane >> 3;
    const bool isK = (w < 2);
    const us* gA = (w == 0) ? Kgh : (w == 1) ? Kgl : (w == 2) ? Vgh : Vgl;
    us* lbase = sm + w * 4096;

    f32x4 oacc[4];
#pragma unroll
    for (int j = 0; j < 4; ++j)
#pragma unroll
        for (int r = 0; r < 4; ++r) oacc[j][r] = 0.f;
    float mrun = -1e30f, lrun = 0.f;

    for (int t = 0; t < SS / 64; ++t) {
        __syncthreads();
        if (isK) {
#pragma unroll
            for (int i = 0; i < 8; ++i) {
                const int row = i * 8 + rsub;
                const us* g = gA + (size_t)(t * 64 + row) * 512 + ((fp ^ (row & 7)) << 3);
                gload_lds16(g, lbase + i * 512);
            }
        } else {
#pragma unroll
            for (int i = 0; i < 8; ++i) {
                const int row = i * 8 + rsub;
                const us* g = gA + (size_t)row * 1024 + t * 64 + ((fp ^ (row & 7)) << 3);
                gload_lds16(g, lbase + i * 512);
            }
        }
        __syncthreads();

        f32x4 stt[4];
#pragma unroll
        for (int fs = 0; fs < 4; ++fs)
#pragma unroll
            for (int r = 0; r < 4; ++r) stt[fs][r] = 0.f;
        __builtin_amdgcn_s_setprio(1);
#pragma unroll
        for (int ks = 0; ks < 2; ++ks) {
            short8 kfh[4], kfl[4];
#pragma unroll
            for (int fs = 0; fs < 4; ++fs) {
                const int row = fs * 16 + fr;
                const int off = row * 128 + (((ks * 4 + fq4) ^ (row & 7)) << 4);
                kfh[fs] = *(const short8*)((const char*)sKh + off);
                kfl[fs] = *(const short8*)((const char*)sKl + off);
            }
#pragma unroll
            for (int fs = 0; fs < 4; ++fs) {
                stt[fs] = __builtin_amdgcn_mfma_f32_16x16x32_bf16(kfh[fs], qfh[ks], stt[fs], 0, 0, 0);
                stt[fs] = __builtin_amdgcn_mfma_f32_16x16x32_bf16(kfh[fs], qfl[ks], stt[fs], 0, 0, 0);
                stt[fs] = __builtin_amdgcn_mfma_f32_16x16x32_bf16(kfl[fs], qfh[ks], stt[fs], 0, 0, 0);
            }
        }
        __builtin_amdgcn_s_setprio(0);

        // ---- online softmax; scales live in-lane, distributed via __shfl
        float mx = stt[0][0];
#pragma unroll
        for (int fs = 0; fs < 4; ++fs)
#pragma unroll
            for (int r = 0; r < 4; ++r) mx = fmaxf(mx, stt[fs][r]);
        mx = fmaxf(mx, __shfl_xor(mx, 16));
        mx = fmaxf(mx, __shfl_xor(mx, 32));
        const bool grow = __any(mx > mrun);
        float scf = 1.f;
        if (grow) {
            const float nm = fmaxf(mrun, mx);
            scf = __expf(mrun - nm);
            mrun = nm;
        }
        float ps = 0.f;
#pragma unroll
        for (int fs = 0; fs < 4; ++fs)
#pragma unroll
            for (int r = 0; r < 4; ++r) {
                const float p = __expf(stt[fs][r] - mrun);
                stt[fs][r] = p;
                ps += p;
            }
        ps += __shfl_xor(ps, 16);
        ps += __shfl_xor(ps, 32);
        lrun = lrun * scf + ps;

        // ---- write P[q][s] hi only (wave-private rows)
#pragma unroll
        for (int fs = 0; fs < 4; ++fs) {
            const int q = w * 16 + fr;
            const int flog = (fs << 1) | (fq4 >> 1);
            const int off = q * 128 + ((flog ^ (q & 7)) << 4) + ((fq4 & 1) << 3);
            *(uint2*)((char*)sPh + off) = pack4_hi(stt[fs][0], stt[fs][1],
                                                  stt[fs][2], stt[fs][3]);
        }

        // ---- rescale oacc via shfl (row q=fq4*4+r lives in lane fq4*4+r)
        if (grow) {
#pragma unroll
            for (int r = 0; r < 4; ++r) {
                const float scv = __shfl(scf, fq4 * 4 + r);
#pragma unroll
                for (int fd = 0; fd < 4; ++fd) oacc[fd][r] *= scv;
            }
        }

        // ---- PV: 2-term (Ph*Vh + Ph*Vl)
        __builtin_amdgcn_s_setprio(1);
#pragma unroll
        for (int ks = 0; ks < 2; ++ks) {
            short8 pfh, vfh[4], vfl[4];
            {
                const int row = w * 16 + fr;
                const int off = row * 128 + (((ks * 4 + fq4) ^ (row & 7)) << 4);
                pfh = *(const short8*)((const char*)sPh + off);
            }
#pragma unroll
            for (int fd = 0; fd < 4; ++fd) {
                const int row = fd * 16 + fr;
                const int off = row * 128 + (((ks * 4 + fq4) ^ (row & 7)) << 4);
                vfh[fd] = *(const short8*)((const char*)sVh + off);
                vfl[fd] = *(const short8*)((const char*)sVl + off);
            }
#pragma unroll
            for (int fd = 0; fd < 4; ++fd) {
                oacc[fd] = __builtin_amdgcn_mfma_f32_16x16x32_bf16(pfh, vfh[fd], oacc[fd], 0, 0, 0);
                oacc[fd] = __builtin_amdgcn_mfma_f32_16x16x32_bf16(pfh, vfl[fd], oacc[fd], 0, 0, 0);
            }
        }
        __builtin_amdgcn_s_setprio(0);
    }

    // ---- normalize + store pre-split (lrun distributed via shfl)
#pragma unroll
    for (int r = 0; r < 4; ++r) {
        const float inv = 1.0f / __shfl(lrun, fq4 * 4 + r);
        const int q = w * 16 + fq4 * 4 + r;
#pragma unroll
        for (int fd = 0; fd < 4; ++fd) {
            const float v = oacc[fd][r] * inv;
            const us hv = bf_hi(v);
            Oh[(size_t)q * 512 + fd * 16 + fr] = hv;
            Ol[(size_t)q * 512 + fd * 16 + fr] = bf_hi(v - bf_f(hv));
        }
    }
}

// ---------------------------------------------------------------------------
// MERGED argmax + update: 8 blocks; 4-way partial accumulators break the
// serial FMA dependency chains (latency-bound kernel).
// ---------------------------------------------------------------------------
__global__ __launch_bounds__(256) void argmax_update(
    const float* __restrict__ rm,
    const float* __restrict__ mb, const float* __restrict__ ni,
    const float* __restrict__ Wu1, const float* __restrict__ bu1,
    const float* __restrict__ Wu2, const float* __restrict__ bu2,
    const float* __restrict__ wwp, const int* __restrict__ s_star,
    const int* __restrict__ exists, float* __restrict__ outu)
{
    const int b = blockIdx.x, tid = threadIdx.x;
    __shared__ float comb[2 * DD];
    __shared__ float hu[HH];
    __shared__ float sv[4]; __shared__ int si[4];
    __shared__ int spos;

    {
        float best = -3.0e38f; int bidx = 1 << 30;
        for (int m = tid; m < MM; m += 256) {
            const float v = rm[b * MM + m];
            if (v > best || (v == best && m < bidx)) { best = v; bidx = m; }
        }
#pragma unroll
        for (int msk = 1; msk < 64; msk <<= 1) {
            const float ov = __shfl_xor(best, msk);
            const int oi = __shfl_xor(bidx, msk);
            if (ov > best || (ov == best && oi < bidx)) { best = ov; bidx = oi; }
        }
        if ((tid & 63) == 0) { sv[tid >> 6] = best; si[tid >> 6] = bidx; }
        __syncthreads();
        if (tid == 0) {
            for (int w = 1; w < 4; ++w)
                if (sv[w] > best || (sv[w] == best && si[w] < bidx)) { best = sv[w]; bidx = si[w]; }
            spos = bidx;
        }
        __syncthreads();
    }

    const int p = spos, ss = s_star[b], ex = exists[b];
    const float* oldp = mb + ((size_t)(b * MM + p)) * DD;
    const float* selp = ni + ((size_t)(b * SS + ss)) * DD;
    for (int i = tid; i < DD; i += 256) { comb[i] = oldp[i]; comb[DD + i] = selp[i]; }
    __syncthreads();
#pragma unroll
    for (int t = 0; t < 2; ++t) {
        const int n = tid + t * 256;
        float a0 = 0.f, a1 = 0.f, a2 = 0.f, a3 = 0.f;
        for (int k = 0; k < 2 * DD; k += 4) {
            a0 = fmaf(comb[k + 0], Wu1[(size_t)(k + 0) * HH + n], a0);
            a1 = fmaf(comb[k + 1], Wu1[(size_t)(k + 1) * HH + n], a1);
            a2 = fmaf(comb[k + 2], Wu1[(size_t)(k + 2) * HH + n], a2);
            a3 = fmaf(comb[k + 3], Wu1[(size_t)(k + 3) * HH + n], a3);
        }
        hu[n] = fmaxf(bu1[n] + ((a0 + a1) + (a2 + a3)), 0.f);
    }
    __syncthreads();
#pragma unroll
    for (int t = 0; t < 2; ++t) {
        const int n = tid + t * 256;
        float a0 = 0.f, a1 = 0.f, a2 = 0.f, a3 = 0.f;
        for (int k = 0; k < HH; k += 4) {
            a0 = fmaf(hu[k + 0], Wu2[(size_t)(k + 0) * HH + n], a0);
            a1 = fmaf(hu[k + 1], Wu2[(size_t)(k + 1) * HH + n], a1);
            a2 = fmaf(hu[k + 2], Wu2[(size_t)(k + 2) * HH + n], a2);
            a3 = fmaf(hu[k + 3], Wu2[(size_t)(k + 3) * HH + n], a3);
        }
        const float upd = tanhf(bu2[n] + ((a0 + a1) + (a2 + a3)));
        const float wwv = wwp[((size_t)(b * MM + p)) * HH + n];
        const float ov = oldp[n];
        outu[((size_t)(b * MM + p)) * DD + n] = ex ? fmaf(upd, wwv, ov) : ov;
    }
}

extern "C" void kernel_launch(void* const* d_in, const int* in_sizes, int n_in,
                              void* d_out, int out_size, void* d_ws, size_t ws_size,
                              hipStream_t stream)
{
    const float* new_info    = (const float*)d_in[0];
    const float* memory_bank = (const float*)d_in[1];
    const float* W_in = (const float*)d_in[2];  const float* b_in = (const float*)d_in[3];
    const float* Wq   = (const float*)d_in[4];  const float* bq   = (const float*)d_in[5];
    const float* Wk   = (const float*)d_in[6];  const float* bk   = (const float*)d_in[7];
    const float* Wv   = (const float*)d_in[8];  const float* bv   = (const float*)d_in[9];
    const float* Wo   = (const float*)d_in[10]; const float* bo   = (const float*)d_in[11];
    const float* Wi1  = (const float*)d_in[12]; const float* bi1  = (const float*)d_in[13];
    const float* Wi2  = (const float*)d_in[14]; const float* bi2  = (const float*)d_in[15];
    const float* Wu1  = (const float*)d_in[16]; const float* bu1  = (const float*)d_in[17];
    const float* Wu2  = (const float*)d_in[18]; const float* bu2  = (const float*)d_in[19];

    float* out = (float*)d_out;
    float* out_updated = out;                               // B*M*D
    float* out_ww      = out + (size_t)BB * MM * HH;        // B*M*H
    float* out_imp     = out + 2 * (size_t)BB * MM * HH;    // B*S

    // workspace layout (f32 units), ~125 MB
    float* ws = (float*)d_ws;
    float* qsp_rg    = ws;                                  // 8,388,608 (qsph/qspl)
    float* ip_sp     = qsp_rg + 8388608;                    // 4,194,304 (iph/ipl)
    float* mb_sp     = ip_sp + 4194304;                     // 8,388,608 (mbh/mbl; attn out reuses)
    float* kvreg     = mb_sp + 8388608;                     // 8,388,608 (K/V splits)
    float* wtf       = kvreg + 8388608;                     // 1,703,936 (us pairs)
    float* bq_eff    = wtf + 1703936;                       // 512
    float* bkv       = bq_eff + 512;                        // 1024
    float* rowmeanv  = bkv + 1024;                          // 16,384 (zeroed w/ logit)
    float* logit     = rowmeanv + 16384;                    // 8,192
    float* imp_mean  = logit + 8192;                        // 8
    int*   istar     = (int*)(imp_mean + BB);
    int*   iexists   = istar + BB;

    us* qsph = (us*)qsp_rg;        // [16384][512]
    us* qspl = qsph + 8388608;
    us* iph = (us*)ip_sp;          // [8192][512]
    us* ipl = iph + 4194304;
    us* mbh = (us*)mb_sp;          // [16384][512]
    us* mbl = mbh + 8388608;
    us* Kh  = (us*)kvreg;          // [8192][512]
    us* Kl  = Kh + 4194304;
    us* Vth = Kl + 4194304;        // [8][512][1024]
    us* Vtl = Vth + 4194304;

    us* wtin_h  = (us*)wtf;            us* wtin_l  = wtin_h + 262144;
    us* wtq_h   = wtin_l + 262144;     us* wtq_l   = wtq_h + 262144;
    us* wtkv_h  = wtq_l + 262144;      us* wtkv_l  = wtkv_h + 524288;   // [1024][512]
    us* wto_h   = wtkv_l + 524288;     us* wto_l   = wto_h + 262144;
    us* wtinq_h = wto_l + 262144;      us* wtinq_l = wtinq_h + 262144;
    us* wti1_h  = wtinq_l + 262144;    us* wti1_l  = wti1_h + 131072;   // [256][512]

    const dim3 blk(256);

    // 1) merged prep: mb copy+split, zero rowmeanv+logit, bkv, bq_eff, 6x transpose
    TSB ts;
    ts.src[0] = W_in; ts.dh[0] = wtin_h;          ts.dl[0] = wtin_l;          ts.nc[0] = 512;
    ts.src[1] = Wq;   ts.dh[1] = wtq_h;           ts.dl[1] = wtq_l;           ts.nc[1] = 512;
    ts.src[2] = Wk;   ts.dh[2] = wtkv_h;          ts.dl[2] = wtkv_l;          ts.nc[2] = 512;
    ts.src[3] = Wv;   ts.dh[3] = wtkv_h + 262144; ts.dl[3] = wtkv_l + 262144; ts.nc[3] = 512;
    ts.src[4] = Wo;   ts.dh[4] = wto_h;           ts.dl[4] = wto_l;           ts.nc[4] = 512;
    ts.src[5] = Wi1;  ts.dh[5] = wti1_h;          ts.dl[5] = wti1_l;          ts.nc[5] = 256;
    prep_all<<<dim3(2066 + 1536), blk, 0, stream>>>(memory_bank, out_updated,
                                                    mbh, mbl, 1048576, rowmeanv,
                                                    bk, bv, bkv, b_in, Wq, bq,
                                                    bq_eff, ts);

    // 2) merged info-GEMM (pre-split out) + winq-GEMM (transposed-split out)
    gemm_info_winq<<<dim3(272), blk, 0, stream>>>(new_info, wtin_h, wtin_l, b_in,
                                                  iph, ipl, W_in, wtq_h, wtq_l,
                                                  wtinq_h, wtinq_l);

    // 3) merged Q-GEMM + KV-GEMM + h1-logit GEMM (1152 blocks)
    gemm_qkvh1_ps<<<dim3(1152), blk, 0, stream>>>(mbh, mbl, wtinq_h, wtinq_l,
                                                  bq_eff, qsph, qspl,
                                                  iph, ipl, wtkv_h, wtkv_l, bkv,
                                                  Kh, Kl, Vth, Vtl,
                                                  wti1_h, wti1_l, bi1, Wi2, logit);

    // 4) MFMA flash attention (2048) + fused importance finalize (8)
    attn_mfma<<<dim3(2056), blk, 0, stream>>>(qsph, qspl, Kh, Kl, Vth, Vtl,
                                              mbh, mbl, logit, bi2, out_imp,
                                              imp_mean, istar, iexists);

    // 5) output projection + imp_mean rowscale + fused rowmean
    gemm_wo_ps<<<dim3(4, 128), blk, 0, stream>>>(mbh, mbl, wto_h, wto_l,
                                                 bo, out_ww, imp_mean, rowmeanv);

    // 6) merged argmax + final row update
    argmax_update<<<dim3(BB), blk, 0, stream>>>(rowmeanv, memory_bank, new_info,
                                                Wu1, bu1, Wu2, bu2, out_ww,
                                                istar, iexists, out_updated);
}